// Round 10
// baseline (2282.006 us; speedup 1.0000x reference)
//
#include <hip/hip_runtime.h>

#define MTOK 8192      // B*S
#define HD   768
#define H3   2304
#define NL   6
#define TT   32        // CRF tags (reference: T = 32)

typedef __attribute__((ext_vector_type(4))) float f32x4;
typedef __attribute__((ext_vector_type(8))) short v8bf;     // 8 bf16 in 4 VGPRs
typedef __attribute__((ext_vector_type(4))) unsigned short us4;
typedef __attribute__((ext_vector_type(8))) unsigned short us8;

__device__ __forceinline__ unsigned short bf16rne(float v) {
    unsigned int u = __float_as_uint(v);
    u += 0x7FFFu + ((u >> 16) & 1u);
    return (unsigned short)(u >> 16);
}
__device__ __forceinline__ float bf2f(unsigned short h) {
    return __uint_as_float(((unsigned int)h) << 16);
}
// hi bf16 in low 16 bits, mid (residual) bf16 in high 16 bits
__device__ __forceinline__ unsigned int split_pack(float v) {
    unsigned short h = bf16rne(v);
    unsigned short m = bf16rne(v - bf2f(h));
    return (unsigned int)h | ((unsigned int)m << 16);
}

// async global->LDS, 16B per lane, LDS dest = wave-uniform base + lane*16
__device__ __forceinline__ void gload16(const unsigned short* g, unsigned short* l) {
    __builtin_amdgcn_global_load_lds(
        (const __attribute__((address_space(1))) unsigned int*)g,
        (__attribute__((address_space(3))) unsigned int*)l, 16, 0, 0);
}

// ---------------------------------------------------------------------------
// Fused weight split for one layer: in_w (2304x768), out_w, w1, w2 (768x768).
// ---------------------------------------------------------------------------
__global__ __launch_bounds__(256)
void wsplit4_kernel(const float* __restrict__ inw, const float* __restrict__ outw,
                    const float* __restrict__ w1, const float* __restrict__ w2,
                    unsigned short* __restrict__ wih, unsigned short* __restrict__ wim,
                    unsigned short* __restrict__ woh, unsigned short* __restrict__ wom,
                    unsigned short* __restrict__ w1h, unsigned short* __restrict__ w1m,
                    unsigned short* __restrict__ w2h, unsigned short* __restrict__ w2m)
{
    int i = blockIdx.x * 256 + threadIdx.x;      // 884736 float4 total
    const float* src; unsigned short* dh; unsigned short* dm; int off;
    if (i < 442368)      { src = inw;  dh = wih; dm = wim; off = i; }
    else if (i < 589824) { src = outw; dh = woh; dm = wom; off = i - 442368; }
    else if (i < 737280) { src = w1;   dh = w1h; dm = w1m; off = i - 589824; }
    else                 { src = w2;   dh = w2h; dm = w2m; off = i - 737280; }
    float4 v = reinterpret_cast<const float4*>(src)[off];
    us4 hv, mv; unsigned int p;
    p = split_pack(v.x); hv[0] = (unsigned short)p; mv[0] = (unsigned short)(p >> 16);
    p = split_pack(v.y); hv[1] = (unsigned short)p; mv[1] = (unsigned short)(p >> 16);
    p = split_pack(v.z); hv[2] = (unsigned short)p; mv[2] = (unsigned short)(p >> 16);
    p = split_pack(v.w); hv[3] = (unsigned short)p; mv[3] = (unsigned short)(p >> 16);
    reinterpret_cast<us4*>(dh)[off] = hv;
    reinterpret_cast<us4*>(dm)[off] = mv;
}

// ---------------------------------------------------------------------------
// GEMM on pre-split operands, 3 products (hh, hm, mh). XCD-swizzled grid.
// ---------------------------------------------------------------------------
template<bool RELU, bool SPLITOUT>
__global__ __launch_bounds__(256)
void gemm_pair_kernel(const unsigned short* __restrict__ Ahg, const unsigned short* __restrict__ Amg,
                      const unsigned short* __restrict__ Bhg, const unsigned short* __restrict__ Bmg,
                      const float* __restrict__ bias, float* __restrict__ Cf,
                      unsigned short* __restrict__ Ch, unsigned short* __restrict__ Cm, int N)
{
    __shared__ unsigned short lds[4][128 * 64];   // Ah, Am, Bh, Bm tiles (64 KB)
    const int tid = threadIdx.x;
    const int lane = tid & 63, wave = tid >> 6;
    const int wm = wave >> 1, wn = wave & 1;
    // bijective XCD swizzle (grid total % 8 == 0)
    const int nbx = gridDim.x;
    const int total = nbx * gridDim.y;
    const int flat = blockIdx.y * nbx + blockIdx.x;
    const int sw = (flat & 7) * (total >> 3) + (flat >> 3);
    const int bn = sw % nbx, bm = sw / nbx;
    const int g = lane >> 4, lr = lane & 15;

    const int srow = lane >> 3;
    const int schunk = ((lane & 7) ^ srow) * 8;   // pre-swizzled source chunk (shorts)
    const size_t aoff = ((size_t)(bm * 128 + wave * 32 + srow)) * HD + schunk;
    const size_t boff = ((size_t)(bn * 128 + wave * 32 + srow)) * HD + schunk;

    f32x4 acc[4][4] = {};

    for (int kt = 0; kt < 12; ++kt) {
        __syncthreads();
        const int k64 = kt * 64;
        #pragma unroll
        for (int i = 0; i < 4; ++i) {
            const size_t ra = aoff + (size_t)i * 8 * HD + k64;
            const size_t rb = boff + (size_t)i * 8 * HD + k64;
            unsigned short* lb = (unsigned short*)&lds[0][(wave * 32 + i * 8) * 64];
            gload16(Ahg + ra, lb);
            gload16(Amg + ra, lb + 8192);
            gload16(Bhg + rb, lb + 16384);
            gload16(Bmg + rb, lb + 24576);
        }
        __syncthreads();
        #pragma unroll
        for (int kk = 0; kk < 2; ++kk) {
            v8bf ah[4], am[4], bh[4], bmv[4];
            #pragma unroll
            for (int i = 0; i < 4; ++i) {
                int row = wm * 64 + i * 16 + lr;
                int ub = row * 64 + ((((kk << 2) + g) ^ (row & 7)) << 3);
                ah[i] = *reinterpret_cast<const v8bf*>(&lds[0][ub]);
                am[i] = *reinterpret_cast<const v8bf*>(&lds[1][ub]);
            }
            #pragma unroll
            for (int i = 0; i < 4; ++i) {
                int row = wn * 64 + i * 16 + lr;
                int ub = row * 64 + ((((kk << 2) + g) ^ (row & 7)) << 3);
                bh[i]  = *reinterpret_cast<const v8bf*>(&lds[2][ub]);
                bmv[i] = *reinterpret_cast<const v8bf*>(&lds[3][ub]);
            }
            #pragma unroll
            for (int i = 0; i < 4; ++i)
                #pragma unroll
                for (int j = 0; j < 4; ++j) {
                    acc[i][j] = __builtin_amdgcn_mfma_f32_16x16x32_bf16(ah[i], bh[j],  acc[i][j], 0, 0, 0);
                    acc[i][j] = __builtin_amdgcn_mfma_f32_16x16x32_bf16(ah[i], bmv[j], acc[i][j], 0, 0, 0);
                    acc[i][j] = __builtin_amdgcn_mfma_f32_16x16x32_bf16(am[i], bh[j],  acc[i][j], 0, 0, 0);
                }
        }
    }
    #pragma unroll
    for (int j = 0; j < 4; ++j) {
        int n = bn * 128 + wn * 64 + j * 16 + lr;
        float bv = bias[n];
        #pragma unroll
        for (int i = 0; i < 4; ++i) {
            int mr = bm * 128 + wm * 64 + i * 16 + 4 * g;
            #pragma unroll
            for (int r = 0; r < 4; ++r) {
                float y = acc[i][j][r] + bv;
                if (RELU) y = fmaxf(y, 0.0f);
                size_t idx = (size_t)(mr + r) * N + n;
                if (SPLITOUT) {
                    unsigned int pk = split_pack(y);
                    Ch[idx] = (unsigned short)pk;
                    Cm[idx] = (unsigned short)(pk >> 16);
                } else {
                    Cf[idx] = y;
                }
            }
        }
    }
}

// ---------------------------------------------------------------------------
// V transpose: qkv V-part [tok][h*64+d] -> vt[bh][d][s]. Grid (8 kt, 192 bh).
// ---------------------------------------------------------------------------
__global__ __launch_bounds__(256)
void vtrans_kernel(const unsigned short* __restrict__ qh, const unsigned short* __restrict__ qm,
                   unsigned short* __restrict__ vth, unsigned short* __restrict__ vtm)
{
    __shared__ unsigned short Th[4096], Tm[4096];
    const int kt = blockIdx.x, bh = blockIdx.y;
    const int b = bh / 12, h = bh % 12;
    const int tid = threadIdx.x;
    #pragma unroll
    for (int is = 0; is < 2; ++is) {
        int c = is * 256 + tid;
        int r = c >> 3, dc = c & 7;
        size_t src = ((size_t)b * 512 + kt * 64 + r) * H3 + 1536 + h * 64 + dc * 8;
        int swz = (dc ^ (r & 7) ^ (r >> 3)) * 8;
        *reinterpret_cast<us8*>(&Th[r * 64 + swz]) = *reinterpret_cast<const us8*>(&qh[src]);
        *reinterpret_cast<us8*>(&Tm[r * 64 + swz]) = *reinterpret_cast<const us8*>(&qm[src]);
    }
    __syncthreads();
    #pragma unroll
    for (int is = 0; is < 2; ++is) {
        int c = is * 256 + tid;
        int d = c >> 3, rg = c & 7;
        us8 vh, vm;
        #pragma unroll
        for (int e = 0; e < 8; ++e) {
            int r = rg * 8 + e;
            int addr = r * 64 + (((d >> 3) ^ (r & 7) ^ (r >> 3)) * 8) + (d & 7);
            vh[e] = Th[addr]; vm[e] = Tm[addr];
        }
        size_t dst = ((size_t)bh * 64 + d) * 512 + kt * 64 + rg * 8;
        *reinterpret_cast<us8*>(&vth[dst]) = vh;
        *reinterpret_cast<us8*>(&vtm[dst]) = vm;
    }
}

// ---------------------------------------------------------------------------
// Flash attention v2. Grid (2 q-halves, 192 bh), 4 waves; wave owns 64 q-rows.
// ---------------------------------------------------------------------------
__global__ __launch_bounds__(256, 2)
void attn_kernel(const unsigned short* __restrict__ qh, const unsigned short* __restrict__ qm,
                 const unsigned short* __restrict__ vth, const unsigned short* __restrict__ vtm,
                 unsigned short* __restrict__ ohp, unsigned short* __restrict__ omp)
{
    __shared__ unsigned short Kh[4096], Km[4096], Vh[4096], Vm[4096];
    __shared__ unsigned short Ph[4][1024], Pm[4][1024];
    const int qhalf = blockIdx.x;
    const int bh = blockIdx.y;
    const int b = bh / 12, h = bh % 12;
    const int tid = threadIdx.x, lane = tid & 63, wave = tid >> 6;
    const int g = lane >> 4, lr = lane & 15;
    const size_t rowbase = (size_t)b * 512;
    const int qbase = qhalf * 256 + wave * 64;

    v8bf aqh[4][2], aqm[4][2];
    #pragma unroll
    for (int i = 0; i < 4; ++i)
        #pragma unroll
        for (int kk = 0; kk < 2; ++kk) {
            size_t a = (rowbase + qbase + i * 16 + lr) * H3 + h * 64 + (kk * 4 + g) * 8;
            aqh[i][kk] = *reinterpret_cast<const v8bf*>(&qh[a]);
            aqm[i][kk] = *reinterpret_cast<const v8bf*>(&qm[a]);
        }

    float m_run[4][4], l_run[4][4];
    f32x4 O[4][4];
    #pragma unroll
    for (int i = 0; i < 4; ++i)
        #pragma unroll
        for (int r = 0; r < 4; ++r) {
            m_run[i][r] = -__builtin_inff(); l_run[i][r] = 0.0f;
            O[i][r] = (f32x4){0.0f, 0.0f, 0.0f, 0.0f};
        }

    const int srow = lane >> 3;
    const int schunk = ((lane & 7) ^ srow) * 8;

    for (int kt = 0; kt < 8; ++kt) {
        __syncthreads();
        #pragma unroll
        for (int is = 0; is < 2; ++is) {
            int rowg = is * 32 + wave * 8;
            size_t ksrc = (rowbase + kt * 64 + rowg + srow) * H3 + 768 + h * 64 + schunk;
            size_t vsrc = ((size_t)bh * 64 + rowg + srow) * 512 + kt * 64 + schunk;
            gload16(qh + ksrc, &Kh[rowg * 64]);
            gload16(qm + ksrc, &Km[rowg * 64]);
            gload16(vth + vsrc, &Vh[rowg * 64]);
            gload16(vtm + vsrc, &Vm[rowg * 64]);
        }
        __syncthreads();

        #pragma unroll
        for (int i = 0; i < 4; ++i) {
            f32x4 s[4] = {};
            #pragma unroll
            for (int kk = 0; kk < 2; ++kk) {
                #pragma unroll
                for (int j = 0; j < 4; ++j) {
                    int krow = j * 16 + lr;
                    int uk = krow * 64 + (((kk * 4 + g) ^ (krow & 7)) * 8);
                    v8bf bkh = *reinterpret_cast<const v8bf*>(&Kh[uk]);
                    v8bf bkm = *reinterpret_cast<const v8bf*>(&Km[uk]);
                    s[j] = __builtin_amdgcn_mfma_f32_16x16x32_bf16(aqh[i][kk], bkh, s[j], 0, 0, 0);
                    s[j] = __builtin_amdgcn_mfma_f32_16x16x32_bf16(aqh[i][kk], bkm, s[j], 0, 0, 0);
                    s[j] = __builtin_amdgcn_mfma_f32_16x16x32_bf16(aqm[i][kk], bkh, s[j], 0, 0, 0);
                }
            }
            float mnew[4], alpha[4], rsum[4];
            #pragma unroll
            for (int rr = 0; rr < 4; ++rr) {
                float t = fmaxf(fmaxf(s[0][rr], s[1][rr]), fmaxf(s[2][rr], s[3][rr])) * 0.125f;
                #pragma unroll
                for (int off = 1; off < 16; off <<= 1) t = fmaxf(t, __shfl_xor(t, off));
                mnew[rr] = fmaxf(m_run[i][rr], t);
                alpha[rr] = __expf(m_run[i][rr] - mnew[rr]);
                m_run[i][rr] = mnew[rr];
                rsum[rr] = 0.0f;
            }
            #pragma unroll
            for (int j = 0; j < 4; ++j) {
                #pragma unroll
                for (int rr = 0; rr < 4; ++rr) {
                    float p = __expf(s[j][rr] * 0.125f - mnew[rr]);
                    rsum[rr] += p;
                    int prow = 4 * g + rr;
                    int ub = prow * 64 + ((((j * 2 + (lr >> 3)) ^ (prow & 7)) << 3) | (lr & 7));
                    unsigned int pk = split_pack(p);
                    Ph[wave][ub] = (unsigned short)pk; Pm[wave][ub] = (unsigned short)(pk >> 16);
                }
            }
            #pragma unroll
            for (int rr = 0; rr < 4; ++rr) {
                float t = rsum[rr];
                #pragma unroll
                for (int off = 1; off < 16; off <<= 1) t += __shfl_xor(t, off);
                l_run[i][rr] = l_run[i][rr] * alpha[rr] + t;
                O[i][0][rr] *= alpha[rr]; O[i][1][rr] *= alpha[rr];
                O[i][2][rr] *= alpha[rr]; O[i][3][rr] *= alpha[rr];
            }
            #pragma unroll
            for (int kk = 0; kk < 2; ++kk) {
                int up = lr * 64 + (((kk * 4 + g) ^ (lr & 7)) * 8);
                v8bf aph = *reinterpret_cast<const v8bf*>(&Ph[wave][up]);
                v8bf apm = *reinterpret_cast<const v8bf*>(&Pm[wave][up]);
                #pragma unroll
                for (int j = 0; j < 4; ++j) {
                    int vrow = j * 16 + lr;
                    int uv = vrow * 64 + (((kk * 4 + g) ^ (vrow & 7)) * 8);
                    v8bf bvh = *reinterpret_cast<const v8bf*>(&Vh[uv]);
                    v8bf bvm = *reinterpret_cast<const v8bf*>(&Vm[uv]);
                    O[i][j] = __builtin_amdgcn_mfma_f32_16x16x32_bf16(aph, bvh, O[i][j], 0, 0, 0);
                    O[i][j] = __builtin_amdgcn_mfma_f32_16x16x32_bf16(aph, bvm, O[i][j], 0, 0, 0);
                    O[i][j] = __builtin_amdgcn_mfma_f32_16x16x32_bf16(apm, bvh, O[i][j], 0, 0, 0);
                }
            }
        }
    }
    #pragma unroll
    for (int i = 0; i < 4; ++i)
        #pragma unroll
        for (int j = 0; j < 4; ++j) {
            int d = j * 16 + lr;
            #pragma unroll
            for (int rr = 0; rr < 4; ++rr) {
                size_t tok = rowbase + qbase + i * 16 + 4 * g + rr;
                unsigned int pk = split_pack(O[i][j][rr] / l_run[i][rr]);
                ohp[tok * HD + h * 64 + d] = (unsigned short)pk;
                omp[tok * HD + h * 64 + d] = (unsigned short)(pk >> 16);
            }
        }
}

// ---------------------------------------------------------------------------
// x = LayerNorm((xh+xm) + t) * g + b -> (xh, xm). One wave per token.
// ---------------------------------------------------------------------------
__global__ __launch_bounds__(256)
void ln_residual_kernel(unsigned short* __restrict__ xh, unsigned short* __restrict__ xm,
                        const float* __restrict__ t,
                        const float* __restrict__ gamma, const float* __restrict__ beta)
{
    int tok = blockIdx.x * 4 + (threadIdx.x >> 6);
    int lane = threadIdx.x & 63;
    size_t base = (size_t)tok * HD + lane * 12;
    int cb = lane * 12;
    us4 h4[3], m4[3]; f32x4 t4[3];
    #pragma unroll
    for (int q = 0; q < 3; ++q) {
        h4[q] = *reinterpret_cast<const us4*>(&xh[base + q * 4]);
        m4[q] = *reinterpret_cast<const us4*>(&xm[base + q * 4]);
        t4[q] = *reinterpret_cast<const f32x4*>(&t[base + q * 4]);
    }
    float v[12];
    float s = 0.0f;
    #pragma unroll
    for (int k = 0; k < 12; ++k) {
        v[k] = bf2f(h4[k >> 2][k & 3]) + bf2f(m4[k >> 2][k & 3]) + t4[k >> 2][k & 3];
        s += v[k];
    }
    #pragma unroll
    for (int off = 32; off; off >>= 1) s += __shfl_xor(s, off);
    float mean = s * (1.0f / 768.0f);
    float vs = 0.0f;
    #pragma unroll
    for (int k = 0; k < 12; ++k) { float d = v[k] - mean; vs += d * d; }
    #pragma unroll
    for (int off = 32; off; off >>= 1) vs += __shfl_xor(vs, off);
    float rstd = rsqrtf(vs * (1.0f / 768.0f) + 1e-5f);
    f32x4 ga[3], be[3];
    #pragma unroll
    for (int q = 0; q < 3; ++q) {
        ga[q] = *reinterpret_cast<const f32x4*>(&gamma[cb + q * 4]);
        be[q] = *reinterpret_cast<const f32x4*>(&beta[cb + q * 4]);
    }
    us4 oh[3], om[3];
    #pragma unroll
    for (int k = 0; k < 12; ++k) {
        float y = (v[k] - mean) * rstd * ga[k >> 2][k & 3] + be[k >> 2][k & 3];
        unsigned int pk = split_pack(y);
        oh[k >> 2][k & 3] = (unsigned short)pk;
        om[k >> 2][k & 3] = (unsigned short)(pk >> 16);
    }
    #pragma unroll
    for (int q = 0; q < 3; ++q) {
        *reinterpret_cast<us4*>(&xh[base + q * 4]) = oh[q];
        *reinterpret_cast<us4*>(&xm[base + q * 4]) = om[q];
    }
}

__global__ __launch_bounds__(256)
void embed_kernel(const int* __restrict__ ids, const float* __restrict__ emb,
                  unsigned short* __restrict__ xh, unsigned short* __restrict__ xm)
{
    int f4 = blockIdx.x * 256 + threadIdx.x;     // 8192*192 float4
    int tok = f4 / 192, c = f4 % 192;
    float4 v = *reinterpret_cast<const float4*>(emb + (size_t)ids[tok] * HD + c * 4);
    us4 hv, mv; unsigned int p;
    p = split_pack(v.x); hv[0] = (unsigned short)p; mv[0] = (unsigned short)(p >> 16);
    p = split_pack(v.y); hv[1] = (unsigned short)p; mv[1] = (unsigned short)(p >> 16);
    p = split_pack(v.z); hv[2] = (unsigned short)p; mv[2] = (unsigned short)(p >> 16);
    p = split_pack(v.w); hv[3] = (unsigned short)p; mv[3] = (unsigned short)(p >> 16);
    *reinterpret_cast<us4*>(&xh[(size_t)tok * HD + c * 4]) = hv;
    *reinterpret_cast<us4*>(&xm[(size_t)tok * HD + c * 4]) = mv;
}

// logits f32 = xh + xm
__global__ __launch_bounds__(256)
void out_logits_kernel(const unsigned short* __restrict__ xh, const unsigned short* __restrict__ xm,
                       float* __restrict__ out)
{
    int i = blockIdx.x * 256 + threadIdx.x;
    us4 hv = reinterpret_cast<const us4*>(xh)[i];
    us4 mv = reinterpret_cast<const us4*>(xm)[i];
    float4 o;
    o.x = bf2f(hv[0]) + bf2f(mv[0]);
    o.y = bf2f(hv[1]) + bf2f(mv[1]);
    o.z = bf2f(hv[2]) + bf2f(mv[2]);
    o.w = bf2f(hv[3]) + bf2f(mv[3]);
    reinterpret_cast<float4*>(out)[i] = o;
}

// emis[tok][t] = dot768(x[tok], head_w[t]) + head_b[t] — wave per token
__global__ __launch_bounds__(256)
void emis_kernel(const unsigned short* __restrict__ xh, const unsigned short* __restrict__ xm,
                 const float* __restrict__ hw, const float* __restrict__ hb,
                 float* __restrict__ emis)
{
    int tok = blockIdx.x * 4 + (threadIdx.x >> 6);
    int lane = threadIdx.x & 63;
    size_t base = (size_t)tok * HD + lane * 12;
    int cb = lane * 12;
    us4 h4[3], m4[3];
    #pragma unroll
    for (int q = 0; q < 3; ++q) {
        h4[q] = *reinterpret_cast<const us4*>(&xh[base + q * 4]);
        m4[q] = *reinterpret_cast<const us4*>(&xm[base + q * 4]);
    }
    float xv[12];
    #pragma unroll
    for (int k = 0; k < 12; ++k)
        xv[k] = bf2f(h4[k >> 2][k & 3]) + bf2f(m4[k >> 2][k & 3]);
    for (int t = 0; t < TT; ++t) {
        f32x4 w4[3];
        #pragma unroll
        for (int q = 0; q < 3; ++q)
            w4[q] = *reinterpret_cast<const f32x4*>(&hw[t * HD + cb + q * 4]);
        float a = 0.0f;
        #pragma unroll
        for (int k = 0; k < 12; ++k) a += xv[k] * w4[k >> 2][k & 3];
        #pragma unroll
        for (int off = 32; off; off >>= 1) a += __shfl_xor(a, off);
        if (lane == 0) emis[(size_t)tok * TT + t] = a + hb[t];
    }
}

__global__ void crf_num_kernel(const float* __restrict__ emis, const int* __restrict__ labels,
                               const float* __restrict__ start, const float* __restrict__ end,
                               const float* __restrict__ trans, float* __restrict__ num)
{
    int b = blockIdx.x, lane = threadIdx.x;   // blockDim 64
    float a = 0.0f;
    for (int s = lane; s < 512; s += 64) {
        int lab = labels[b * 512 + s];
        a += emis[(size_t)(b * 512 + s) * TT + lab];
        if (s > 0) a += trans[labels[b * 512 + s - 1] * TT + lab];
        else a += start[lab];
        if (s == 511) a += end[lab];
    }
    #pragma unroll
    for (int off = 32; off; off >>= 1) a += __shfl_xor(a, off);
    if (lane == 0) num[b] = a;
}

// ---------------------------------------------------------------------------
// Fused CRF forward + viterbi v5. Cross-lane broadcast via v_readlane into
// SGPRs — no LDS round-trip in the recursion chain (v4's remaining cost).
// Viterbi values/tree order identical to v4 -> tags bit-identical.
// ---------------------------------------------------------------------------
__global__ __launch_bounds__(64)
void crf_path_kernel(const float* __restrict__ emis, const float* __restrict__ start,
                     const float* __restrict__ end, const float* __restrict__ trans,
                     float* __restrict__ logZ, float* __restrict__ out_tags)
{
    const int mode = blockIdx.x >> 4;
    const int b = blockIdx.x & 15;
    const int lane = threadIdx.x;
    const int j = lane & 31;
    __shared__ float shist[512 * 32];            // viterbi score history (64 KB)
    __shared__ unsigned char hist[511][32];
    __shared__ float sval[32];
    __shared__ int path[512];

    const float* eb = emis + (size_t)b * 512 * TT;

    if (mode == 0) {
        if (lane < 32) {
            float Ecol[32];
            #pragma unroll
            for (int ii = 0; ii < 32; ++ii) Ecol[ii] = __expf(trans[ii * TT + j]);
            float cur[8], nxt[8];
            #pragma unroll
            for (int i = 0; i < 8; ++i) cur[i] = eb[(1 + i) * TT + j];
            float sc = start[j] + eb[j];
            for (int base = 1; base < 512; base += 8) {
                #pragma unroll
                for (int i = 0; i < 8; ++i) {
                    int s = base + 8 + i;
                    nxt[i] = eb[(s < 512 ? s : 511) * TT + j];
                }
                #pragma unroll
                for (int i = 0; i < 8; ++i) {
                    if (base + i < 512) {
                        unsigned int su = __float_as_uint(sc);
                        float r = __uint_as_float(__builtin_amdgcn_readfirstlane(su));
                        float p = __expf(sc - r);
                        unsigned int pu = __float_as_uint(p);
                        float ps[32];
                        #pragma unroll
                        for (int ii = 0; ii < 32; ++ii)
                            ps[ii] = __uint_as_float(__builtin_amdgcn_readlane(pu, ii));
                        float mm[16];
                        #pragma unroll
                        for (int q = 0; q < 16; ++q)
                            mm[q] = fmaf(ps[2 * q + 1], Ecol[2 * q + 1],
                                         ps[2 * q] * Ecol[2 * q]);
                        float s8[8];
                        #pragma unroll
                        for (int q = 0; q < 8; ++q) s8[q] = mm[2 * q] + mm[2 * q + 1];
                        float s4[4];
                        #pragma unroll
                        for (int q = 0; q < 4; ++q) s4[q] = s8[2 * q] + s8[2 * q + 1];
                        float dot = (s4[0] + s4[1]) + (s4[2] + s4[3]);
                        sc = r + __logf(dot) + cur[i];
                    }
                }
                #pragma unroll
                for (int i = 0; i < 8; ++i) cur[i] = nxt[i];
            }
            float v = sc + end[j];
            float mx = v;
            #pragma unroll
            for (int off = 1; off < 32; off <<= 1) mx = fmaxf(mx, __shfl_xor(mx, off));
            float p = __expf(v - mx);
            float sm = p;
            #pragma unroll
            for (int off = 1; off < 32; off <<= 1) sm += __shfl_xor(sm, off);
            if (lane == 0) logZ[b] = mx + __logf(sm);
        }
    } else {
        // all 64 lanes preload trans column j (lanes j and j+32 share j)
        float tcol[32];
        #pragma unroll
        for (int ii = 0; ii < 32; ++ii) tcol[ii] = trans[ii * TT + j];

        // phase 1 (lanes 0..31): value-max recursion via readlane broadcast
        if (lane < 32) {
            float cur[8], nxt[8];
            #pragma unroll
            for (int i = 0; i < 8; ++i) cur[i] = eb[(1 + i) * TT + j];
            float sc = start[j] + eb[j];
            shist[0 * 32 + j] = sc;
            for (int base = 1; base < 512; base += 8) {
                #pragma unroll
                for (int i = 0; i < 8; ++i) {
                    int s = base + 8 + i;
                    nxt[i] = eb[(s < 512 ? s : 511) * TT + j];
                }
                #pragma unroll
                for (int i = 0; i < 8; ++i) {
                    if (base + i < 512) {
                        unsigned int su = __float_as_uint(sc);
                        float c[32];
                        #pragma unroll
                        for (int ii = 0; ii < 32; ++ii)
                            c[ii] = __uint_as_float(__builtin_amdgcn_readlane(su, ii))
                                    + tcol[ii];
                        float v1[16];
                        #pragma unroll
                        for (int q = 0; q < 16; ++q) v1[q] = fmaxf(c[2 * q], c[2 * q + 1]);
                        float v2[8];
                        #pragma unroll
                        for (int q = 0; q < 8; ++q) v2[q] = fmaxf(v1[2 * q], v1[2 * q + 1]);
                        float v3[4];
                        #pragma unroll
                        for (int q = 0; q < 4; ++q) v3[q] = fmaxf(v2[2 * q], v2[2 * q + 1]);
                        float best = fmaxf(fmaxf(v3[0], v3[1]), fmaxf(v3[2], v3[3]));
                        sc = best + cur[i];
                        shist[(base + i) * 32 + j] = sc;
                    }
                }
                #pragma unroll
                for (int i = 0; i < 8; ++i) cur[i] = nxt[i];
            }
            sval[j] = sc + end[j];
        }
        __syncthreads();

        // phase 2 (all 64 lanes): argmax table, first-max semantics
        const int h = lane >> 5;
        for (int it = 0; it < 256; ++it) {
            int s = 1 + 2 * it + h;
            if (s < 512) {
                const float* pr = &shist[(s - 1) * 32];
                float c[32];
                #pragma unroll
                for (int q = 0; q < 8; ++q) {
                    f32x4 t4 = *reinterpret_cast<const f32x4*>(&pr[q * 4]);
                    c[q * 4 + 0] = t4[0] + tcol[q * 4 + 0];
                    c[q * 4 + 1] = t4[1] + tcol[q * 4 + 1];
                    c[q * 4 + 2] = t4[2] + tcol[q * 4 + 2];
                    c[q * 4 + 3] = t4[3] + tcol[q * 4 + 3];
                }
                float v1[16]; int a1[16];
                #pragma unroll
                for (int q = 0; q < 16; ++q) {
                    bool ge = c[2 * q] >= c[2 * q + 1];
                    v1[q] = ge ? c[2 * q] : c[2 * q + 1];
                    a1[q] = ge ? 2 * q : 2 * q + 1;
                }
                float v2[8]; int a2[8];
                #pragma unroll
                for (int q = 0; q < 8; ++q) {
                    bool ge = v1[2 * q] >= v1[2 * q + 1];
                    v2[q] = ge ? v1[2 * q] : v1[2 * q + 1];
                    a2[q] = ge ? a1[2 * q] : a1[2 * q + 1];
                }
                float v3[4]; int a3[4];
                #pragma unroll
                for (int q = 0; q < 4; ++q) {
                    bool ge = v2[2 * q] >= v2[2 * q + 1];
                    v3[q] = ge ? v2[2 * q] : v2[2 * q + 1];
                    a3[q] = ge ? a2[2 * q] : a2[2 * q + 1];
                }
                float v4[2]; int a4[2];
                #pragma unroll
                for (int q = 0; q < 2; ++q) {
                    bool ge = v3[2 * q] >= v3[2 * q + 1];
                    v4[q] = ge ? v3[2 * q] : v3[2 * q + 1];
                    a4[q] = ge ? a3[2 * q] : a3[2 * q + 1];
                }
                bool ge = v4[0] >= v4[1];
                int arg = ge ? a4[0] : a4[1];
                hist[s - 1][j] = (unsigned char)arg;
            }
        }
        __syncthreads();

        if (lane == 0) {
            float best = sval[0]; int arg = 0;
            for (int i = 1; i < TT; ++i)
                if (sval[i] > best) { best = sval[i]; arg = i; }
            int t = arg; path[511] = t;
            for (int s = 510; s >= 0; --s) { t = hist[s][t]; path[s] = t; }
        }
        __syncthreads();
        for (int s = lane; s < 512; s += 64)
            out_tags[(size_t)b * 512 + s] = (float)path[s];
    }
}

__global__ void crf_loss_kernel(const float* __restrict__ num, const float* __restrict__ logZ,
                                float* __restrict__ out)
{
    if (threadIdx.x == 0) {
        float s = 0.0f;
        for (int b = 0; b < 16; ++b) s += num[b] - logZ[b];
        out[0] = -s / 10000.0f;
    }
}

extern "C" void kernel_launch(void* const* d_in, const int* in_sizes, int n_in,
                              void* d_out, int out_size, void* d_ws, size_t ws_size,
                              hipStream_t stream)
{
    (void)in_sizes; (void)n_in; (void)out_size; (void)ws_size;
    const int*   input_ids = (const int*)d_in[0];
    const int*   labels    = (const int*)d_in[1];
    const float* emb   = (const float*)d_in[3];
    const float* in_w  = (const float*)d_in[4];
    const float* in_b  = (const float*)d_in[5];
    const float* out_w = (const float*)d_in[6];
    const float* out_b = (const float*)d_in[7];
    const float* ln1g  = (const float*)d_in[8];
    const float* ln1b  = (const float*)d_in[9];
    const float* ln2g  = (const float*)d_in[10];
    const float* ln2b  = (const float*)d_in[11];
    const float* w1    = (const float*)d_in[12];
    const float* b1    = (const float*)d_in[13];
    const float* w2    = (const float*)d_in[14];
    const float* b2    = (const float*)d_in[15];
    const float* hw    = (const float*)d_in[16];
    const float* hb    = (const float*)d_in[17];
    const float* cs    = (const float*)d_in[18];
    const float* ce    = (const float*)d_in[19];
    const float* ct    = (const float*)d_in[20];
    float* out = (float*)d_out;

    char* ws = (char*)d_ws;
    unsigned short* xh   = (unsigned short*)(ws);
    unsigned short* xm   = (unsigned short*)(ws + 12582912);
    unsigned short* qkvh = (unsigned short*)(ws + 25165824);
    unsigned short* qkvm = (unsigned short*)(ws + 62914560);
    unsigned short* ohb  = (unsigned short*)(ws + 100663296);
    unsigned short* omb  = (unsigned short*)(ws + 113246208);
    float*          tmp  = (float*)(ws + 125829120);
    unsigned short* vth  = (unsigned short*)(ws + 125829120);  // alias tmp (disjoint lifetime)
    unsigned short* vtm  = (unsigned short*)(ws + 138412032);
    unsigned short* wih  = (unsigned short*)(ws + 150994944);
    unsigned short* wim  = (unsigned short*)(ws + 154533888);
    unsigned short* woh  = (unsigned short*)(ws + 158072832);
    unsigned short* wom  = (unsigned short*)(ws + 159252480);
    unsigned short* w1h  = (unsigned short*)(ws + 160432128);
    unsigned short* w1m  = (unsigned short*)(ws + 161611776);
    unsigned short* w2h  = (unsigned short*)(ws + 162791424);
    unsigned short* w2m  = (unsigned short*)(ws + 163971072);
    unsigned short* f1h  = qkvh;   // qkv dead after attn
    unsigned short* f1m  = qkvm;
    float* emis = (float*)(ws + 100663296);                // alias ohb (dead post-encoder)
    float* numb = (float*)(ws + 100663296 + 1048576);
    float* logZ = numb + 16;

    embed_kernel<<<MTOK * 192 / 256, 256, 0, stream>>>(input_ids, emb, xh, xm);

    for (int l = 0; l < NL; ++l) {
        wsplit4_kernel<<<3456, 256, 0, stream>>>(
            in_w + (size_t)l * H3 * HD, out_w + (size_t)l * HD * HD,
            w1 + (size_t)l * HD * HD, w2 + (size_t)l * HD * HD,
            wih, wim, woh, wom, w1h, w1m, w2h, w2m);

        gemm_pair_kernel<false, true><<<dim3(18, 64), 256, 0, stream>>>(
            xh, xm, wih, wim, in_b + (size_t)l * H3, nullptr, qkvh, qkvm, H3);
        vtrans_kernel<<<dim3(8, 192), 256, 0, stream>>>(qkvh, qkvm, vth, vtm);
        attn_kernel<<<dim3(2, 192), 256, 0, stream>>>(qkvh, qkvm, vth, vtm, ohb, omb);
        gemm_pair_kernel<false, false><<<dim3(6, 64), 256, 0, stream>>>(
            ohb, omb, woh, wom, out_b + (size_t)l * HD, tmp, nullptr, nullptr, HD);
        ln_residual_kernel<<<2048, 256, 0, stream>>>(xh, xm, tmp, ln1g + l * HD, ln1b + l * HD);
        gemm_pair_kernel<true, true><<<dim3(6, 64), 256, 0, stream>>>(
            xh, xm, w1h, w1m, b1 + (size_t)l * HD, nullptr, f1h, f1m, HD);
        gemm_pair_kernel<false, false><<<dim3(6, 64), 256, 0, stream>>>(
            f1h, f1m, w2h, w2m, b2 + (size_t)l * HD, tmp, nullptr, nullptr, HD);
        ln_residual_kernel<<<2048, 256, 0, stream>>>(xh, xm, tmp, ln2g + l * HD, ln2b + l * HD);
    }

    out_logits_kernel<<<MTOK * 192 / 256, 256, 0, stream>>>(xh, xm, out);

    emis_kernel<<<2048, 256, 0, stream>>>(xh, xm, hw, hb, emis);
    crf_num_kernel<<<16, 64, 0, stream>>>(emis, labels, cs, ce, ct, numb);
    crf_path_kernel<<<32, 64, 0, stream>>>(emis, cs, ce, ct, logZ, out + 6291457);
    crf_loss_kernel<<<1, 64, 0, stream>>>(numb, logZ, out + 6291456);
}

// Round 11
// 2232.531 us; speedup vs baseline: 1.0222x; 1.0222x over previous
//
#include <hip/hip_runtime.h>

#define MTOK 8192      // B*S
#define HD   768
#define H3   2304
#define NL   6
#define TT   32        // CRF tags (reference: T = 32)

typedef __attribute__((ext_vector_type(4))) float f32x4;
typedef __attribute__((ext_vector_type(8))) short v8bf;     // 8 bf16 in 4 VGPRs
typedef __attribute__((ext_vector_type(4))) unsigned short us4;
typedef __attribute__((ext_vector_type(8))) unsigned short us8;

__device__ __forceinline__ unsigned short bf16rne(float v) {
    unsigned int u = __float_as_uint(v);
    u += 0x7FFFu + ((u >> 16) & 1u);
    return (unsigned short)(u >> 16);
}
__device__ __forceinline__ float bf2f(unsigned short h) {
    return __uint_as_float(((unsigned int)h) << 16);
}
// hi bf16 in low 16 bits, mid (residual) bf16 in high 16 bits
__device__ __forceinline__ unsigned int split_pack(float v) {
    unsigned short h = bf16rne(v);
    unsigned short m = bf16rne(v - bf2f(h));
    return (unsigned int)h | ((unsigned int)m << 16);
}

// async global->LDS, 16B per lane, LDS dest = wave-uniform base + lane*16
__device__ __forceinline__ void gload16(const unsigned short* g, unsigned short* l) {
    __builtin_amdgcn_global_load_lds(
        (const __attribute__((address_space(1))) unsigned int*)g,
        (__attribute__((address_space(3))) unsigned int*)l, 16, 0, 0);
}

// ---------------------------------------------------------------------------
// Fused weight split for one layer: in_w (2304x768), out_w, w1, w2 (768x768).
// ---------------------------------------------------------------------------
__global__ __launch_bounds__(256)
void wsplit4_kernel(const float* __restrict__ inw, const float* __restrict__ outw,
                    const float* __restrict__ w1, const float* __restrict__ w2,
                    unsigned short* __restrict__ wih, unsigned short* __restrict__ wim,
                    unsigned short* __restrict__ woh, unsigned short* __restrict__ wom,
                    unsigned short* __restrict__ w1h, unsigned short* __restrict__ w1m,
                    unsigned short* __restrict__ w2h, unsigned short* __restrict__ w2m)
{
    int i = blockIdx.x * 256 + threadIdx.x;      // 884736 float4 total
    const float* src; unsigned short* dh; unsigned short* dm; int off;
    if (i < 442368)      { src = inw;  dh = wih; dm = wim; off = i; }
    else if (i < 589824) { src = outw; dh = woh; dm = wom; off = i - 442368; }
    else if (i < 737280) { src = w1;   dh = w1h; dm = w1m; off = i - 589824; }
    else                 { src = w2;   dh = w2h; dm = w2m; off = i - 737280; }
    float4 v = reinterpret_cast<const float4*>(src)[off];
    us4 hv, mv; unsigned int p;
    p = split_pack(v.x); hv[0] = (unsigned short)p; mv[0] = (unsigned short)(p >> 16);
    p = split_pack(v.y); hv[1] = (unsigned short)p; mv[1] = (unsigned short)(p >> 16);
    p = split_pack(v.z); hv[2] = (unsigned short)p; mv[2] = (unsigned short)(p >> 16);
    p = split_pack(v.w); hv[3] = (unsigned short)p; mv[3] = (unsigned short)(p >> 16);
    reinterpret_cast<us4*>(dh)[off] = hv;
    reinterpret_cast<us4*>(dm)[off] = mv;
}

// ---------------------------------------------------------------------------
// GEMM on pre-split operands, 3 products (hh, hm, mh). XCD-swizzled grid.
// ---------------------------------------------------------------------------
template<bool RELU, bool SPLITOUT>
__global__ __launch_bounds__(256)
void gemm_pair_kernel(const unsigned short* __restrict__ Ahg, const unsigned short* __restrict__ Amg,
                      const unsigned short* __restrict__ Bhg, const unsigned short* __restrict__ Bmg,
                      const float* __restrict__ bias, float* __restrict__ Cf,
                      unsigned short* __restrict__ Ch, unsigned short* __restrict__ Cm, int N)
{
    __shared__ unsigned short lds[4][128 * 64];   // Ah, Am, Bh, Bm tiles (64 KB)
    const int tid = threadIdx.x;
    const int lane = tid & 63, wave = tid >> 6;
    const int wm = wave >> 1, wn = wave & 1;
    // bijective XCD swizzle (grid total % 8 == 0)
    const int nbx = gridDim.x;
    const int total = nbx * gridDim.y;
    const int flat = blockIdx.y * nbx + blockIdx.x;
    const int sw = (flat & 7) * (total >> 3) + (flat >> 3);
    const int bn = sw % nbx, bm = sw / nbx;
    const int g = lane >> 4, lr = lane & 15;

    const int srow = lane >> 3;
    const int schunk = ((lane & 7) ^ srow) * 8;   // pre-swizzled source chunk (shorts)
    const size_t aoff = ((size_t)(bm * 128 + wave * 32 + srow)) * HD + schunk;
    const size_t boff = ((size_t)(bn * 128 + wave * 32 + srow)) * HD + schunk;

    f32x4 acc[4][4] = {};

    for (int kt = 0; kt < 12; ++kt) {
        __syncthreads();
        const int k64 = kt * 64;
        #pragma unroll
        for (int i = 0; i < 4; ++i) {
            const size_t ra = aoff + (size_t)i * 8 * HD + k64;
            const size_t rb = boff + (size_t)i * 8 * HD + k64;
            unsigned short* lb = (unsigned short*)&lds[0][(wave * 32 + i * 8) * 64];
            gload16(Ahg + ra, lb);
            gload16(Amg + ra, lb + 8192);
            gload16(Bhg + rb, lb + 16384);
            gload16(Bmg + rb, lb + 24576);
        }
        __syncthreads();
        #pragma unroll
        for (int kk = 0; kk < 2; ++kk) {
            v8bf ah[4], am[4], bh[4], bmv[4];
            #pragma unroll
            for (int i = 0; i < 4; ++i) {
                int row = wm * 64 + i * 16 + lr;
                int ub = row * 64 + ((((kk << 2) + g) ^ (row & 7)) << 3);
                ah[i] = *reinterpret_cast<const v8bf*>(&lds[0][ub]);
                am[i] = *reinterpret_cast<const v8bf*>(&lds[1][ub]);
            }
            #pragma unroll
            for (int i = 0; i < 4; ++i) {
                int row = wn * 64 + i * 16 + lr;
                int ub = row * 64 + ((((kk << 2) + g) ^ (row & 7)) << 3);
                bh[i]  = *reinterpret_cast<const v8bf*>(&lds[2][ub]);
                bmv[i] = *reinterpret_cast<const v8bf*>(&lds[3][ub]);
            }
            #pragma unroll
            for (int i = 0; i < 4; ++i)
                #pragma unroll
                for (int j = 0; j < 4; ++j) {
                    acc[i][j] = __builtin_amdgcn_mfma_f32_16x16x32_bf16(ah[i], bh[j],  acc[i][j], 0, 0, 0);
                    acc[i][j] = __builtin_amdgcn_mfma_f32_16x16x32_bf16(ah[i], bmv[j], acc[i][j], 0, 0, 0);
                    acc[i][j] = __builtin_amdgcn_mfma_f32_16x16x32_bf16(am[i], bh[j],  acc[i][j], 0, 0, 0);
                }
        }
    }
    #pragma unroll
    for (int j = 0; j < 4; ++j) {
        int n = bn * 128 + wn * 64 + j * 16 + lr;
        float bv = bias[n];
        #pragma unroll
        for (int i = 0; i < 4; ++i) {
            int mr = bm * 128 + wm * 64 + i * 16 + 4 * g;
            #pragma unroll
            for (int r = 0; r < 4; ++r) {
                float y = acc[i][j][r] + bv;
                if (RELU) y = fmaxf(y, 0.0f);
                size_t idx = (size_t)(mr + r) * N + n;
                if (SPLITOUT) {
                    unsigned int pk = split_pack(y);
                    Ch[idx] = (unsigned short)pk;
                    Cm[idx] = (unsigned short)(pk >> 16);
                } else {
                    Cf[idx] = y;
                }
            }
        }
    }
}

// ---------------------------------------------------------------------------
// V transpose: qkv V-part [tok][h*64+d] -> vt[bh][d][s]. Grid (8 kt, 192 bh).
// ---------------------------------------------------------------------------
__global__ __launch_bounds__(256)
void vtrans_kernel(const unsigned short* __restrict__ qh, const unsigned short* __restrict__ qm,
                   unsigned short* __restrict__ vth, unsigned short* __restrict__ vtm)
{
    __shared__ unsigned short Th[4096], Tm[4096];
    const int kt = blockIdx.x, bh = blockIdx.y;
    const int b = bh / 12, h = bh % 12;
    const int tid = threadIdx.x;
    #pragma unroll
    for (int is = 0; is < 2; ++is) {
        int c = is * 256 + tid;
        int r = c >> 3, dc = c & 7;
        size_t src = ((size_t)b * 512 + kt * 64 + r) * H3 + 1536 + h * 64 + dc * 8;
        int swz = (dc ^ (r & 7) ^ (r >> 3)) * 8;
        *reinterpret_cast<us8*>(&Th[r * 64 + swz]) = *reinterpret_cast<const us8*>(&qh[src]);
        *reinterpret_cast<us8*>(&Tm[r * 64 + swz]) = *reinterpret_cast<const us8*>(&qm[src]);
    }
    __syncthreads();
    #pragma unroll
    for (int is = 0; is < 2; ++is) {
        int c = is * 256 + tid;
        int d = c >> 3, rg = c & 7;
        us8 vh, vm;
        #pragma unroll
        for (int e = 0; e < 8; ++e) {
            int r = rg * 8 + e;
            int addr = r * 64 + (((d >> 3) ^ (r & 7) ^ (r >> 3)) * 8) + (d & 7);
            vh[e] = Th[addr]; vm[e] = Tm[addr];
        }
        size_t dst = ((size_t)bh * 64 + d) * 512 + kt * 64 + rg * 8;
        *reinterpret_cast<us8*>(&vth[dst]) = vh;
        *reinterpret_cast<us8*>(&vtm[dst]) = vm;
    }
}

// ---------------------------------------------------------------------------
// Flash attention v2. Grid (2 q-halves, 192 bh), 4 waves; wave owns 64 q-rows.
// ---------------------------------------------------------------------------
__global__ __launch_bounds__(256, 2)
void attn_kernel(const unsigned short* __restrict__ qh, const unsigned short* __restrict__ qm,
                 const unsigned short* __restrict__ vth, const unsigned short* __restrict__ vtm,
                 unsigned short* __restrict__ ohp, unsigned short* __restrict__ omp)
{
    __shared__ unsigned short Kh[4096], Km[4096], Vh[4096], Vm[4096];
    __shared__ unsigned short Ph[4][1024], Pm[4][1024];
    const int qhalf = blockIdx.x;
    const int bh = blockIdx.y;
    const int b = bh / 12, h = bh % 12;
    const int tid = threadIdx.x, lane = tid & 63, wave = tid >> 6;
    const int g = lane >> 4, lr = lane & 15;
    const size_t rowbase = (size_t)b * 512;
    const int qbase = qhalf * 256 + wave * 64;

    v8bf aqh[4][2], aqm[4][2];
    #pragma unroll
    for (int i = 0; i < 4; ++i)
        #pragma unroll
        for (int kk = 0; kk < 2; ++kk) {
            size_t a = (rowbase + qbase + i * 16 + lr) * H3 + h * 64 + (kk * 4 + g) * 8;
            aqh[i][kk] = *reinterpret_cast<const v8bf*>(&qh[a]);
            aqm[i][kk] = *reinterpret_cast<const v8bf*>(&qm[a]);
        }

    float m_run[4][4], l_run[4][4];
    f32x4 O[4][4];
    #pragma unroll
    for (int i = 0; i < 4; ++i)
        #pragma unroll
        for (int r = 0; r < 4; ++r) {
            m_run[i][r] = -__builtin_inff(); l_run[i][r] = 0.0f;
            O[i][r] = (f32x4){0.0f, 0.0f, 0.0f, 0.0f};
        }

    const int srow = lane >> 3;
    const int schunk = ((lane & 7) ^ srow) * 8;

    for (int kt = 0; kt < 8; ++kt) {
        __syncthreads();
        #pragma unroll
        for (int is = 0; is < 2; ++is) {
            int rowg = is * 32 + wave * 8;
            size_t ksrc = (rowbase + kt * 64 + rowg + srow) * H3 + 768 + h * 64 + schunk;
            size_t vsrc = ((size_t)bh * 64 + rowg + srow) * 512 + kt * 64 + schunk;
            gload16(qh + ksrc, &Kh[rowg * 64]);
            gload16(qm + ksrc, &Km[rowg * 64]);
            gload16(vth + vsrc, &Vh[rowg * 64]);
            gload16(vtm + vsrc, &Vm[rowg * 64]);
        }
        __syncthreads();

        #pragma unroll
        for (int i = 0; i < 4; ++i) {
            f32x4 s[4] = {};
            #pragma unroll
            for (int kk = 0; kk < 2; ++kk) {
                #pragma unroll
                for (int j = 0; j < 4; ++j) {
                    int krow = j * 16 + lr;
                    int uk = krow * 64 + (((kk * 4 + g) ^ (krow & 7)) * 8);
                    v8bf bkh = *reinterpret_cast<const v8bf*>(&Kh[uk]);
                    v8bf bkm = *reinterpret_cast<const v8bf*>(&Km[uk]);
                    s[j] = __builtin_amdgcn_mfma_f32_16x16x32_bf16(aqh[i][kk], bkh, s[j], 0, 0, 0);
                    s[j] = __builtin_amdgcn_mfma_f32_16x16x32_bf16(aqh[i][kk], bkm, s[j], 0, 0, 0);
                    s[j] = __builtin_amdgcn_mfma_f32_16x16x32_bf16(aqm[i][kk], bkh, s[j], 0, 0, 0);
                }
            }
            float mnew[4], alpha[4], rsum[4];
            #pragma unroll
            for (int rr = 0; rr < 4; ++rr) {
                float t = fmaxf(fmaxf(s[0][rr], s[1][rr]), fmaxf(s[2][rr], s[3][rr])) * 0.125f;
                #pragma unroll
                for (int off = 1; off < 16; off <<= 1) t = fmaxf(t, __shfl_xor(t, off));
                mnew[rr] = fmaxf(m_run[i][rr], t);
                alpha[rr] = __expf(m_run[i][rr] - mnew[rr]);
                m_run[i][rr] = mnew[rr];
                rsum[rr] = 0.0f;
            }
            #pragma unroll
            for (int j = 0; j < 4; ++j) {
                #pragma unroll
                for (int rr = 0; rr < 4; ++rr) {
                    float p = __expf(s[j][rr] * 0.125f - mnew[rr]);
                    rsum[rr] += p;
                    int prow = 4 * g + rr;
                    int ub = prow * 64 + ((((j * 2 + (lr >> 3)) ^ (prow & 7)) << 3) | (lr & 7));
                    unsigned int pk = split_pack(p);
                    Ph[wave][ub] = (unsigned short)pk; Pm[wave][ub] = (unsigned short)(pk >> 16);
                }
            }
            #pragma unroll
            for (int rr = 0; rr < 4; ++rr) {
                float t = rsum[rr];
                #pragma unroll
                for (int off = 1; off < 16; off <<= 1) t += __shfl_xor(t, off);
                l_run[i][rr] = l_run[i][rr] * alpha[rr] + t;
                O[i][0][rr] *= alpha[rr]; O[i][1][rr] *= alpha[rr];
                O[i][2][rr] *= alpha[rr]; O[i][3][rr] *= alpha[rr];
            }
            #pragma unroll
            for (int kk = 0; kk < 2; ++kk) {
                int up = lr * 64 + (((kk * 4 + g) ^ (lr & 7)) * 8);
                v8bf aph = *reinterpret_cast<const v8bf*>(&Ph[wave][up]);
                v8bf apm = *reinterpret_cast<const v8bf*>(&Pm[wave][up]);
                #pragma unroll
                for (int j = 0; j < 4; ++j) {
                    int vrow = j * 16 + lr;
                    int uv = vrow * 64 + (((kk * 4 + g) ^ (vrow & 7)) * 8);
                    v8bf bvh = *reinterpret_cast<const v8bf*>(&Vh[uv]);
                    v8bf bvm = *reinterpret_cast<const v8bf*>(&Vm[uv]);
                    O[i][j] = __builtin_amdgcn_mfma_f32_16x16x32_bf16(aph, bvh, O[i][j], 0, 0, 0);
                    O[i][j] = __builtin_amdgcn_mfma_f32_16x16x32_bf16(aph, bvm, O[i][j], 0, 0, 0);
                    O[i][j] = __builtin_amdgcn_mfma_f32_16x16x32_bf16(apm, bvh, O[i][j], 0, 0, 0);
                }
            }
        }
    }
    #pragma unroll
    for (int i = 0; i < 4; ++i)
        #pragma unroll
        for (int j = 0; j < 4; ++j) {
            int d = j * 16 + lr;
            #pragma unroll
            for (int rr = 0; rr < 4; ++rr) {
                size_t tok = rowbase + qbase + i * 16 + 4 * g + rr;
                unsigned int pk = split_pack(O[i][j][rr] / l_run[i][rr]);
                ohp[tok * HD + h * 64 + d] = (unsigned short)pk;
                omp[tok * HD + h * 64 + d] = (unsigned short)(pk >> 16);
            }
        }
}

// ---------------------------------------------------------------------------
// x = LayerNorm((xh+xm) + t) * g + b -> (xh, xm). One wave per token.
// ---------------------------------------------------------------------------
__global__ __launch_bounds__(256)
void ln_residual_kernel(unsigned short* __restrict__ xh, unsigned short* __restrict__ xm,
                        const float* __restrict__ t,
                        const float* __restrict__ gamma, const float* __restrict__ beta)
{
    int tok = blockIdx.x * 4 + (threadIdx.x >> 6);
    int lane = threadIdx.x & 63;
    size_t base = (size_t)tok * HD + lane * 12;
    int cb = lane * 12;
    us4 h4[3], m4[3]; f32x4 t4[3];
    #pragma unroll
    for (int q = 0; q < 3; ++q) {
        h4[q] = *reinterpret_cast<const us4*>(&xh[base + q * 4]);
        m4[q] = *reinterpret_cast<const us4*>(&xm[base + q * 4]);
        t4[q] = *reinterpret_cast<const f32x4*>(&t[base + q * 4]);
    }
    float v[12];
    float s = 0.0f;
    #pragma unroll
    for (int k = 0; k < 12; ++k) {
        v[k] = bf2f(h4[k >> 2][k & 3]) + bf2f(m4[k >> 2][k & 3]) + t4[k >> 2][k & 3];
        s += v[k];
    }
    #pragma unroll
    for (int off = 32; off; off >>= 1) s += __shfl_xor(s, off);
    float mean = s * (1.0f / 768.0f);
    float vs = 0.0f;
    #pragma unroll
    for (int k = 0; k < 12; ++k) { float d = v[k] - mean; vs += d * d; }
    #pragma unroll
    for (int off = 32; off; off >>= 1) vs += __shfl_xor(vs, off);
    float rstd = rsqrtf(vs * (1.0f / 768.0f) + 1e-5f);
    f32x4 ga[3], be[3];
    #pragma unroll
    for (int q = 0; q < 3; ++q) {
        ga[q] = *reinterpret_cast<const f32x4*>(&gamma[cb + q * 4]);
        be[q] = *reinterpret_cast<const f32x4*>(&beta[cb + q * 4]);
    }
    us4 oh[3], om[3];
    #pragma unroll
    for (int k = 0; k < 12; ++k) {
        float y = (v[k] - mean) * rstd * ga[k >> 2][k & 3] + be[k >> 2][k & 3];
        unsigned int pk = split_pack(y);
        oh[k >> 2][k & 3] = (unsigned short)pk;
        om[k >> 2][k & 3] = (unsigned short)(pk >> 16);
    }
    #pragma unroll
    for (int q = 0; q < 3; ++q) {
        *reinterpret_cast<us4*>(&xh[base + q * 4]) = oh[q];
        *reinterpret_cast<us4*>(&xm[base + q * 4]) = om[q];
    }
}

__global__ __launch_bounds__(256)
void embed_kernel(const int* __restrict__ ids, const float* __restrict__ emb,
                  unsigned short* __restrict__ xh, unsigned short* __restrict__ xm)
{
    int f4 = blockIdx.x * 256 + threadIdx.x;     // 8192*192 float4
    int tok = f4 / 192, c = f4 % 192;
    float4 v = *reinterpret_cast<const float4*>(emb + (size_t)ids[tok] * HD + c * 4);
    us4 hv, mv; unsigned int p;
    p = split_pack(v.x); hv[0] = (unsigned short)p; mv[0] = (unsigned short)(p >> 16);
    p = split_pack(v.y); hv[1] = (unsigned short)p; mv[1] = (unsigned short)(p >> 16);
    p = split_pack(v.z); hv[2] = (unsigned short)p; mv[2] = (unsigned short)(p >> 16);
    p = split_pack(v.w); hv[3] = (unsigned short)p; mv[3] = (unsigned short)(p >> 16);
    *reinterpret_cast<us4*>(&xh[(size_t)tok * HD + c * 4]) = hv;
    *reinterpret_cast<us4*>(&xm[(size_t)tok * HD + c * 4]) = mv;
}

// ---------------------------------------------------------------------------
// Fused: logits f32 = xh+xm (write to out) AND emis = x @ hw^T + hb.
// One wave per token; x read once.
// ---------------------------------------------------------------------------
__global__ __launch_bounds__(256)
void emis_logits_kernel(const unsigned short* __restrict__ xh, const unsigned short* __restrict__ xm,
                        const float* __restrict__ hw, const float* __restrict__ hb,
                        float* __restrict__ emis, float* __restrict__ out)
{
    int tok = blockIdx.x * 4 + (threadIdx.x >> 6);
    int lane = threadIdx.x & 63;
    size_t base = (size_t)tok * HD + lane * 12;
    int cb = lane * 12;
    us4 h4[3], m4[3];
    #pragma unroll
    for (int q = 0; q < 3; ++q) {
        h4[q] = *reinterpret_cast<const us4*>(&xh[base + q * 4]);
        m4[q] = *reinterpret_cast<const us4*>(&xm[base + q * 4]);
    }
    float xv[12];
    #pragma unroll
    for (int k = 0; k < 12; ++k)
        xv[k] = bf2f(h4[k >> 2][k & 3]) + bf2f(m4[k >> 2][k & 3]);
    // logits write (f32)
    #pragma unroll
    for (int q = 0; q < 3; ++q) {
        f32x4 o;
        o[0] = xv[q * 4 + 0]; o[1] = xv[q * 4 + 1];
        o[2] = xv[q * 4 + 2]; o[3] = xv[q * 4 + 3];
        *reinterpret_cast<f32x4*>(&out[base + q * 4]) = o;
    }
    // emissions
    for (int t = 0; t < TT; ++t) {
        f32x4 w4[3];
        #pragma unroll
        for (int q = 0; q < 3; ++q)
            w4[q] = *reinterpret_cast<const f32x4*>(&hw[t * HD + cb + q * 4]);
        float a = 0.0f;
        #pragma unroll
        for (int k = 0; k < 12; ++k) a += xv[k] * w4[k >> 2][k & 3];
        #pragma unroll
        for (int off = 32; off; off >>= 1) a += __shfl_xor(a, off);
        if (lane == 0) emis[(size_t)tok * TT + t] = a + hb[t];
    }
}

__global__ void crf_num_kernel(const float* __restrict__ emis, const int* __restrict__ labels,
                               const float* __restrict__ start, const float* __restrict__ end,
                               const float* __restrict__ trans, float* __restrict__ num)
{
    int b = blockIdx.x, lane = threadIdx.x;   // blockDim 64
    float a = 0.0f;
    for (int s = lane; s < 512; s += 64) {
        int lab = labels[b * 512 + s];
        a += emis[(size_t)(b * 512 + s) * TT + lab];
        if (s > 0) a += trans[labels[b * 512 + s - 1] * TT + lab];
        else a += start[lab];
        if (s == 511) a += end[lab];
    }
    #pragma unroll
    for (int off = 32; off; off >>= 1) a += __shfl_xor(a, off);
    if (lane == 0) num[b] = a;
}

// ---------------------------------------------------------------------------
// Fused CRF forward + viterbi (v4 — best measured: 214 us).
// Forward: r via readfirstlane, 1 exp/lane, 1 LDS trip, tree dot.
// Viterbi: hot loop = value-max only (exact) + score history in LDS;
//          phase 2 computes the argmax table fully parallel (64 lanes);
//          lane-0 backtrack. Same first-max semantics as the serial reference.
// ---------------------------------------------------------------------------
__global__ __launch_bounds__(64)
void crf_path_kernel(const float* __restrict__ emis, const float* __restrict__ start,
                     const float* __restrict__ end, const float* __restrict__ trans,
                     float* __restrict__ logZ, float* __restrict__ out_tags)
{
    const int mode = blockIdx.x >> 4;
    const int b = blockIdx.x & 15;
    const int lane = threadIdx.x;
    const int j = lane & 31;
    __shared__ float xch[32];
    __shared__ float shist[512 * 32];            // viterbi score history (64 KB)
    __shared__ unsigned char hist[511][32];
    __shared__ float sval[32];
    __shared__ int path[512];

    const float* eb = emis + (size_t)b * 512 * TT;

    if (mode == 0) {
        if (lane < 32) {
            float Ecol[32];
            #pragma unroll
            for (int ii = 0; ii < 32; ++ii) Ecol[ii] = __expf(trans[ii * TT + j]);
            float cur[8], nxt[8];
            #pragma unroll
            for (int i = 0; i < 8; ++i) cur[i] = eb[(1 + i) * TT + j];
            float sc = start[j] + eb[j];
            for (int base = 1; base < 512; base += 8) {
                #pragma unroll
                for (int i = 0; i < 8; ++i) {
                    int s = base + 8 + i;
                    nxt[i] = eb[(s < 512 ? s : 511) * TT + j];
                }
                #pragma unroll
                for (int i = 0; i < 8; ++i) {
                    if (base + i < 512) {
                        float r = __uint_as_float(
                            __builtin_amdgcn_readfirstlane(__float_as_uint(sc)));
                        float p = __expf(sc - r);
                        xch[j] = p;
                        asm volatile("s_waitcnt lgkmcnt(0)" ::: "memory");
                        f32x4 tt[8];
                        #pragma unroll
                        for (int q = 0; q < 8; ++q)
                            tt[q] = *reinterpret_cast<const f32x4*>(&xch[q * 4]);
                        asm volatile("" ::: "memory");
                        float mm[16];
                        #pragma unroll
                        for (int q = 0; q < 16; ++q)
                            mm[q] = fmaf(tt[(2 * q + 1) >> 2][(2 * q + 1) & 3], Ecol[2 * q + 1],
                                         tt[(2 * q) >> 2][(2 * q) & 3] * Ecol[2 * q]);
                        float s8[8];
                        #pragma unroll
                        for (int q = 0; q < 8; ++q) s8[q] = mm[2 * q] + mm[2 * q + 1];
                        float s4[4];
                        #pragma unroll
                        for (int q = 0; q < 4; ++q) s4[q] = s8[2 * q] + s8[2 * q + 1];
                        float dot = (s4[0] + s4[1]) + (s4[2] + s4[3]);
                        sc = r + __logf(dot) + cur[i];
                    }
                }
                #pragma unroll
                for (int i = 0; i < 8; ++i) cur[i] = nxt[i];
            }
            float v = sc + end[j];
            float mx = v;
            #pragma unroll
            for (int off = 1; off < 32; off <<= 1) mx = fmaxf(mx, __shfl_xor(mx, off));
            float p = __expf(v - mx);
            float sm = p;
            #pragma unroll
            for (int off = 1; off < 32; off <<= 1) sm += __shfl_xor(sm, off);
            if (lane == 0) logZ[b] = mx + __logf(sm);
        }
    } else {
        // all 64 lanes preload trans column j (lanes j and j+32 share j)
        float tcol[32];
        #pragma unroll
        for (int ii = 0; ii < 32; ++ii) tcol[ii] = trans[ii * TT + j];

        // phase 1 (lanes 0..31): value-max recursion, store score history
        if (lane < 32) {
            float cur[8], nxt[8];
            #pragma unroll
            for (int i = 0; i < 8; ++i) cur[i] = eb[(1 + i) * TT + j];
            float sc = start[j] + eb[j];
            shist[0 * 32 + j] = sc;
            for (int base = 1; base < 512; base += 8) {
                #pragma unroll
                for (int i = 0; i < 8; ++i) {
                    int s = base + 8 + i;
                    nxt[i] = eb[(s < 512 ? s : 511) * TT + j];
                }
                #pragma unroll
                for (int i = 0; i < 8; ++i) {
                    if (base + i < 512) {
                        xch[j] = sc;
                        asm volatile("s_waitcnt lgkmcnt(0)" ::: "memory");
                        f32x4 tt[8];
                        #pragma unroll
                        for (int q = 0; q < 8; ++q)
                            tt[q] = *reinterpret_cast<const f32x4*>(&xch[q * 4]);
                        asm volatile("" ::: "memory");
                        float c[32];
                        #pragma unroll
                        for (int ii = 0; ii < 32; ++ii)
                            c[ii] = tt[ii >> 2][ii & 3] + tcol[ii];
                        float v1[16];
                        #pragma unroll
                        for (int q = 0; q < 16; ++q) v1[q] = fmaxf(c[2 * q], c[2 * q + 1]);
                        float v2[8];
                        #pragma unroll
                        for (int q = 0; q < 8; ++q) v2[q] = fmaxf(v1[2 * q], v1[2 * q + 1]);
                        float v3[4];
                        #pragma unroll
                        for (int q = 0; q < 4; ++q) v3[q] = fmaxf(v2[2 * q], v2[2 * q + 1]);
                        float best = fmaxf(fmaxf(v3[0], v3[1]), fmaxf(v3[2], v3[3]));
                        sc = best + cur[i];
                        shist[(base + i) * 32 + j] = sc;
                    }
                }
                #pragma unroll
                for (int i = 0; i < 8; ++i) cur[i] = nxt[i];
            }
            sval[j] = sc + end[j];
        }
        __syncthreads();

        // phase 2 (all 64 lanes): argmax table, first-max semantics
        const int h = lane >> 5;
        for (int it = 0; it < 256; ++it) {
            int s = 1 + 2 * it + h;
            if (s < 512) {
                const float* pr = &shist[(s - 1) * 32];
                float c[32];
                #pragma unroll
                for (int q = 0; q < 8; ++q) {
                    f32x4 t4 = *reinterpret_cast<const f32x4*>(&pr[q * 4]);
                    c[q * 4 + 0] = t4[0] + tcol[q * 4 + 0];
                    c[q * 4 + 1] = t4[1] + tcol[q * 4 + 1];
                    c[q * 4 + 2] = t4[2] + tcol[q * 4 + 2];
                    c[q * 4 + 3] = t4[3] + tcol[q * 4 + 3];
                }
                float v1[16]; int a1[16];
                #pragma unroll
                for (int q = 0; q < 16; ++q) {
                    bool ge = c[2 * q] >= c[2 * q + 1];
                    v1[q] = ge ? c[2 * q] : c[2 * q + 1];
                    a1[q] = ge ? 2 * q : 2 * q + 1;
                }
                float v2[8]; int a2[8];
                #pragma unroll
                for (int q = 0; q < 8; ++q) {
                    bool ge = v1[2 * q] >= v1[2 * q + 1];
                    v2[q] = ge ? v1[2 * q] : v1[2 * q + 1];
                    a2[q] = ge ? a1[2 * q] : a1[2 * q + 1];
                }
                float v3[4]; int a3[4];
                #pragma unroll
                for (int q = 0; q < 4; ++q) {
                    bool ge = v2[2 * q] >= v2[2 * q + 1];
                    v3[q] = ge ? v2[2 * q] : v2[2 * q + 1];
                    a3[q] = ge ? a2[2 * q] : a2[2 * q + 1];
                }
                float v4[2]; int a4[2];
                #pragma unroll
                for (int q = 0; q < 2; ++q) {
                    bool ge = v3[2 * q] >= v3[2 * q + 1];
                    v4[q] = ge ? v3[2 * q] : v3[2 * q + 1];
                    a4[q] = ge ? a3[2 * q] : a3[2 * q + 1];
                }
                bool ge = v4[0] >= v4[1];
                int arg = ge ? a4[0] : a4[1];
                hist[s - 1][j] = (unsigned char)arg;
            }
        }
        __syncthreads();

        if (lane == 0) {
            float best = sval[0]; int arg = 0;
            for (int i = 1; i < TT; ++i)
                if (sval[i] > best) { best = sval[i]; arg = i; }
            int t = arg; path[511] = t;
            for (int s = 510; s >= 0; --s) { t = hist[s][t]; path[s] = t; }
        }
        __syncthreads();
        for (int s = lane; s < 512; s += 64)
            out_tags[(size_t)b * 512 + s] = (float)path[s];
    }
}

__global__ void crf_loss_kernel(const float* __restrict__ num, const float* __restrict__ logZ,
                                float* __restrict__ out)
{
    if (threadIdx.x == 0) {
        float s = 0.0f;
        for (int b = 0; b < 16; ++b) s += num[b] - logZ[b];
        out[0] = -s / 10000.0f;
    }
}

extern "C" void kernel_launch(void* const* d_in, const int* in_sizes, int n_in,
                              void* d_out, int out_size, void* d_ws, size_t ws_size,
                              hipStream_t stream)
{
    (void)in_sizes; (void)n_in; (void)out_size; (void)ws_size;
    const int*   input_ids = (const int*)d_in[0];
    const int*   labels    = (const int*)d_in[1];
    const float* emb   = (const float*)d_in[3];
    const float* in_w  = (const float*)d_in[4];
    const float* in_b  = (const float*)d_in[5];
    const float* out_w = (const float*)d_in[6];
    const float* out_b = (const float*)d_in[7];
    const float* ln1g  = (const float*)d_in[8];
    const float* ln1b  = (const float*)d_in[9];
    const float* ln2g  = (const float*)d_in[10];
    const float* ln2b  = (const float*)d_in[11];
    const float* w1    = (const float*)d_in[12];
    const float* b1    = (const float*)d_in[13];
    const float* w2    = (const float*)d_in[14];
    const float* b2    = (const float*)d_in[15];
    const float* hw    = (const float*)d_in[16];
    const float* hb    = (const float*)d_in[17];
    const float* cs    = (const float*)d_in[18];
    const float* ce    = (const float*)d_in[19];
    const float* ct    = (const float*)d_in[20];
    float* out = (float*)d_out;

    char* ws = (char*)d_ws;
    unsigned short* xh   = (unsigned short*)(ws);
    unsigned short* xm   = (unsigned short*)(ws + 12582912);
    unsigned short* qkvh = (unsigned short*)(ws + 25165824);
    unsigned short* qkvm = (unsigned short*)(ws + 62914560);
    unsigned short* ohb  = (unsigned short*)(ws + 100663296);
    unsigned short* omb  = (unsigned short*)(ws + 113246208);
    float*          tmp  = (float*)(ws + 125829120);
    unsigned short* vth  = (unsigned short*)(ws + 125829120);  // alias tmp (disjoint lifetime)
    unsigned short* vtm  = (unsigned short*)(ws + 138412032);
    unsigned short* wih  = (unsigned short*)(ws + 150994944);
    unsigned short* wim  = (unsigned short*)(ws + 154533888);
    unsigned short* woh  = (unsigned short*)(ws + 158072832);
    unsigned short* wom  = (unsigned short*)(ws + 159252480);
    unsigned short* w1h  = (unsigned short*)(ws + 160432128);
    unsigned short* w1m  = (unsigned short*)(ws + 161611776);
    unsigned short* w2h  = (unsigned short*)(ws + 162791424);
    unsigned short* w2m  = (unsigned short*)(ws + 163971072);
    unsigned short* f1h  = qkvh;   // qkv dead after attn
    unsigned short* f1m  = qkvm;
    float* emis = (float*)(ws + 100663296);                // alias ohb (dead post-encoder)
    float* numb = (float*)(ws + 100663296 + 1048576);
    float* logZ = numb + 16;

    embed_kernel<<<MTOK * 192 / 256, 256, 0, stream>>>(input_ids, emb, xh, xm);

    for (int l = 0; l < NL; ++l) {
        wsplit4_kernel<<<3456, 256, 0, stream>>>(
            in_w + (size_t)l * H3 * HD, out_w + (size_t)l * HD * HD,
            w1 + (size_t)l * HD * HD, w2 + (size_t)l * HD * HD,
            wih, wim, woh, wom, w1h, w1m, w2h, w2m);

        gemm_pair_kernel<false, true><<<dim3(18, 64), 256, 0, stream>>>(
            xh, xm, wih, wim, in_b + (size_t)l * H3, nullptr, qkvh, qkvm, H3);
        vtrans_kernel<<<dim3(8, 192), 256, 0, stream>>>(qkvh, qkvm, vth, vtm);
        attn_kernel<<<dim3(2, 192), 256, 0, stream>>>(qkvh, qkvm, vth, vtm, ohb, omb);
        gemm_pair_kernel<false, false><<<dim3(6, 64), 256, 0, stream>>>(
            ohb, omb, woh, wom, out_b + (size_t)l * HD, tmp, nullptr, nullptr, HD);
        ln_residual_kernel<<<2048, 256, 0, stream>>>(xh, xm, tmp, ln1g + l * HD, ln1b + l * HD);
        gemm_pair_kernel<true, true><<<dim3(6, 64), 256, 0, stream>>>(
            xh, xm, w1h, w1m, b1 + (size_t)l * HD, nullptr, f1h, f1m, HD);
        gemm_pair_kernel<false, false><<<dim3(6, 64), 256, 0, stream>>>(
            f1h, f1m, w2h, w2m, b2 + (size_t)l * HD, tmp, nullptr, nullptr, HD);
        ln_residual_kernel<<<2048, 256, 0, stream>>>(xh, xm, tmp, ln2g + l * HD, ln2b + l * HD);
    }

    emis_logits_kernel<<<2048, 256, 0, stream>>>(xh, xm, hw, hb, emis, out);
    crf_num_kernel<<<16, 64, 0, stream>>>(emis, labels, cs, ce, ct, numb);
    crf_path_kernel<<<32, 64, 0, stream>>>(emis, cs, ce, ct, logZ, out + 6291457);
    crf_loss_kernel<<<1, 64, 0, stream>>>(numb, logZ, out + 6291456);
}

// Round 12
// 2231.624 us; speedup vs baseline: 1.0226x; 1.0004x over previous
//
#include <hip/hip_runtime.h>

#define MTOK 8192      // B*S
#define HD   768
#define H3   2304
#define NL   6
#define TT   32        // CRF tags (reference: T = 32)

typedef __attribute__((ext_vector_type(4))) float f32x4;
typedef __attribute__((ext_vector_type(8))) short v8bf;     // 8 bf16 in 4 VGPRs
typedef __attribute__((ext_vector_type(4))) unsigned short us4;
typedef __attribute__((ext_vector_type(8))) unsigned short us8;

__device__ __forceinline__ unsigned short bf16rne(float v) {
    unsigned int u = __float_as_uint(v);
    u += 0x7FFFu + ((u >> 16) & 1u);
    return (unsigned short)(u >> 16);
}
__device__ __forceinline__ float bf2f(unsigned short h) {
    return __uint_as_float(((unsigned int)h) << 16);
}
// hi bf16 in low 16 bits, mid (residual) bf16 in high 16 bits
__device__ __forceinline__ unsigned int split_pack(float v) {
    unsigned short h = bf16rne(v);
    unsigned short m = bf16rne(v - bf2f(h));
    return (unsigned int)h | ((unsigned int)m << 16);
}

// async global->LDS, 16B per lane, LDS dest = wave-uniform base + lane*16
__device__ __forceinline__ void gload16(const unsigned short* g, unsigned short* l) {
    __builtin_amdgcn_global_load_lds(
        (const __attribute__((address_space(1))) unsigned int*)g,
        (__attribute__((address_space(3))) unsigned int*)l, 16, 0, 0);
}

// ---------------------------------------------------------------------------
// Fused weight split for one layer: in_w (2304x768), out_w, w1, w2 (768x768).
// ---------------------------------------------------------------------------
__global__ __launch_bounds__(256)
void wsplit4_kernel(const float* __restrict__ inw, const float* __restrict__ outw,
                    const float* __restrict__ w1, const float* __restrict__ w2,
                    unsigned short* __restrict__ wih, unsigned short* __restrict__ wim,
                    unsigned short* __restrict__ woh, unsigned short* __restrict__ wom,
                    unsigned short* __restrict__ w1h, unsigned short* __restrict__ w1m,
                    unsigned short* __restrict__ w2h, unsigned short* __restrict__ w2m)
{
    int i = blockIdx.x * 256 + threadIdx.x;      // 884736 float4 total
    const float* src; unsigned short* dh; unsigned short* dm; int off;
    if (i < 442368)      { src = inw;  dh = wih; dm = wim; off = i; }
    else if (i < 589824) { src = outw; dh = woh; dm = wom; off = i - 442368; }
    else if (i < 737280) { src = w1;   dh = w1h; dm = w1m; off = i - 589824; }
    else                 { src = w2;   dh = w2h; dm = w2m; off = i - 737280; }
    float4 v = reinterpret_cast<const float4*>(src)[off];
    us4 hv, mv; unsigned int p;
    p = split_pack(v.x); hv[0] = (unsigned short)p; mv[0] = (unsigned short)(p >> 16);
    p = split_pack(v.y); hv[1] = (unsigned short)p; mv[1] = (unsigned short)(p >> 16);
    p = split_pack(v.z); hv[2] = (unsigned short)p; mv[2] = (unsigned short)(p >> 16);
    p = split_pack(v.w); hv[3] = (unsigned short)p; mv[3] = (unsigned short)(p >> 16);
    reinterpret_cast<us4*>(dh)[off] = hv;
    reinterpret_cast<us4*>(dm)[off] = mv;
}

// ---------------------------------------------------------------------------
// GEMM on pre-split operands, 3 products (hh, hm, mh). XCD-swizzled grid.
// ---------------------------------------------------------------------------
template<bool RELU, bool SPLITOUT>
__global__ __launch_bounds__(256)
void gemm_pair_kernel(const unsigned short* __restrict__ Ahg, const unsigned short* __restrict__ Amg,
                      const unsigned short* __restrict__ Bhg, const unsigned short* __restrict__ Bmg,
                      const float* __restrict__ bias, float* __restrict__ Cf,
                      unsigned short* __restrict__ Ch, unsigned short* __restrict__ Cm, int N)
{
    __shared__ unsigned short lds[4][128 * 64];   // Ah, Am, Bh, Bm tiles (64 KB)
    const int tid = threadIdx.x;
    const int lane = tid & 63, wave = tid >> 6;
    const int wm = wave >> 1, wn = wave & 1;
    // bijective XCD swizzle (grid total % 8 == 0)
    const int nbx = gridDim.x;
    const int total = nbx * gridDim.y;
    const int flat = blockIdx.y * nbx + blockIdx.x;
    const int sw = (flat & 7) * (total >> 3) + (flat >> 3);
    const int bn = sw % nbx, bm = sw / nbx;
    const int g = lane >> 4, lr = lane & 15;

    const int srow = lane >> 3;
    const int schunk = ((lane & 7) ^ srow) * 8;   // pre-swizzled source chunk (shorts)
    const size_t aoff = ((size_t)(bm * 128 + wave * 32 + srow)) * HD + schunk;
    const size_t boff = ((size_t)(bn * 128 + wave * 32 + srow)) * HD + schunk;

    f32x4 acc[4][4] = {};

    for (int kt = 0; kt < 12; ++kt) {
        __syncthreads();
        const int k64 = kt * 64;
        #pragma unroll
        for (int i = 0; i < 4; ++i) {
            const size_t ra = aoff + (size_t)i * 8 * HD + k64;
            const size_t rb = boff + (size_t)i * 8 * HD + k64;
            unsigned short* lb = (unsigned short*)&lds[0][(wave * 32 + i * 8) * 64];
            gload16(Ahg + ra, lb);
            gload16(Amg + ra, lb + 8192);
            gload16(Bhg + rb, lb + 16384);
            gload16(Bmg + rb, lb + 24576);
        }
        __syncthreads();
        #pragma unroll
        for (int kk = 0; kk < 2; ++kk) {
            v8bf ah[4], am[4], bh[4], bmv[4];
            #pragma unroll
            for (int i = 0; i < 4; ++i) {
                int row = wm * 64 + i * 16 + lr;
                int ub = row * 64 + ((((kk << 2) + g) ^ (row & 7)) << 3);
                ah[i] = *reinterpret_cast<const v8bf*>(&lds[0][ub]);
                am[i] = *reinterpret_cast<const v8bf*>(&lds[1][ub]);
            }
            #pragma unroll
            for (int i = 0; i < 4; ++i) {
                int row = wn * 64 + i * 16 + lr;
                int ub = row * 64 + ((((kk << 2) + g) ^ (row & 7)) << 3);
                bh[i]  = *reinterpret_cast<const v8bf*>(&lds[2][ub]);
                bmv[i] = *reinterpret_cast<const v8bf*>(&lds[3][ub]);
            }
            #pragma unroll
            for (int i = 0; i < 4; ++i)
                #pragma unroll
                for (int j = 0; j < 4; ++j) {
                    acc[i][j] = __builtin_amdgcn_mfma_f32_16x16x32_bf16(ah[i], bh[j],  acc[i][j], 0, 0, 0);
                    acc[i][j] = __builtin_amdgcn_mfma_f32_16x16x32_bf16(ah[i], bmv[j], acc[i][j], 0, 0, 0);
                    acc[i][j] = __builtin_amdgcn_mfma_f32_16x16x32_bf16(am[i], bh[j],  acc[i][j], 0, 0, 0);
                }
        }
    }
    #pragma unroll
    for (int j = 0; j < 4; ++j) {
        int n = bn * 128 + wn * 64 + j * 16 + lr;
        float bv = bias[n];
        #pragma unroll
        for (int i = 0; i < 4; ++i) {
            int mr = bm * 128 + wm * 64 + i * 16 + 4 * g;
            #pragma unroll
            for (int r = 0; r < 4; ++r) {
                float y = acc[i][j][r] + bv;
                if (RELU) y = fmaxf(y, 0.0f);
                size_t idx = (size_t)(mr + r) * N + n;
                if (SPLITOUT) {
                    unsigned int pk = split_pack(y);
                    Ch[idx] = (unsigned short)pk;
                    Cm[idx] = (unsigned short)(pk >> 16);
                } else {
                    Cf[idx] = y;
                }
            }
        }
    }
}

// ---------------------------------------------------------------------------
// V transpose: qkv V-part [tok][h*64+d] -> vt[bh][d][s]. Grid (8 kt, 192 bh).
// ---------------------------------------------------------------------------
__global__ __launch_bounds__(256)
void vtrans_kernel(const unsigned short* __restrict__ qh, const unsigned short* __restrict__ qm,
                   unsigned short* __restrict__ vth, unsigned short* __restrict__ vtm)
{
    __shared__ unsigned short Th[4096], Tm[4096];
    const int kt = blockIdx.x, bh = blockIdx.y;
    const int b = bh / 12, h = bh % 12;
    const int tid = threadIdx.x;
    #pragma unroll
    for (int is = 0; is < 2; ++is) {
        int c = is * 256 + tid;
        int r = c >> 3, dc = c & 7;
        size_t src = ((size_t)b * 512 + kt * 64 + r) * H3 + 1536 + h * 64 + dc * 8;
        int swz = (dc ^ (r & 7) ^ (r >> 3)) * 8;
        *reinterpret_cast<us8*>(&Th[r * 64 + swz]) = *reinterpret_cast<const us8*>(&qh[src]);
        *reinterpret_cast<us8*>(&Tm[r * 64 + swz]) = *reinterpret_cast<const us8*>(&qm[src]);
    }
    __syncthreads();
    #pragma unroll
    for (int is = 0; is < 2; ++is) {
        int c = is * 256 + tid;
        int d = c >> 3, rg = c & 7;
        us8 vh, vm;
        #pragma unroll
        for (int e = 0; e < 8; ++e) {
            int r = rg * 8 + e;
            int addr = r * 64 + (((d >> 3) ^ (r & 7) ^ (r >> 3)) * 8) + (d & 7);
            vh[e] = Th[addr]; vm[e] = Tm[addr];
        }
        size_t dst = ((size_t)bh * 64 + d) * 512 + kt * 64 + rg * 8;
        *reinterpret_cast<us8*>(&vth[dst]) = vh;
        *reinterpret_cast<us8*>(&vtm[dst]) = vm;
    }
}

// ---------------------------------------------------------------------------
// Flash attention v2. Grid (2 q-halves, 192 bh), 4 waves; wave owns 64 q-rows.
// ---------------------------------------------------------------------------
__global__ __launch_bounds__(256, 2)
void attn_kernel(const unsigned short* __restrict__ qh, const unsigned short* __restrict__ qm,
                 const unsigned short* __restrict__ vth, const unsigned short* __restrict__ vtm,
                 unsigned short* __restrict__ ohp, unsigned short* __restrict__ omp)
{
    __shared__ unsigned short Kh[4096], Km[4096], Vh[4096], Vm[4096];
    __shared__ unsigned short Ph[4][1024], Pm[4][1024];
    const int qhalf = blockIdx.x;
    const int bh = blockIdx.y;
    const int b = bh / 12, h = bh % 12;
    const int tid = threadIdx.x, lane = tid & 63, wave = tid >> 6;
    const int g = lane >> 4, lr = lane & 15;
    const size_t rowbase = (size_t)b * 512;
    const int qbase = qhalf * 256 + wave * 64;

    v8bf aqh[4][2], aqm[4][2];
    #pragma unroll
    for (int i = 0; i < 4; ++i)
        #pragma unroll
        for (int kk = 0; kk < 2; ++kk) {
            size_t a = (rowbase + qbase + i * 16 + lr) * H3 + h * 64 + (kk * 4 + g) * 8;
            aqh[i][kk] = *reinterpret_cast<const v8bf*>(&qh[a]);
            aqm[i][kk] = *reinterpret_cast<const v8bf*>(&qm[a]);
        }

    float m_run[4][4], l_run[4][4];
    f32x4 O[4][4];
    #pragma unroll
    for (int i = 0; i < 4; ++i)
        #pragma unroll
        for (int r = 0; r < 4; ++r) {
            m_run[i][r] = -__builtin_inff(); l_run[i][r] = 0.0f;
            O[i][r] = (f32x4){0.0f, 0.0f, 0.0f, 0.0f};
        }

    const int srow = lane >> 3;
    const int schunk = ((lane & 7) ^ srow) * 8;

    for (int kt = 0; kt < 8; ++kt) {
        __syncthreads();
        #pragma unroll
        for (int is = 0; is < 2; ++is) {
            int rowg = is * 32 + wave * 8;
            size_t ksrc = (rowbase + kt * 64 + rowg + srow) * H3 + 768 + h * 64 + schunk;
            size_t vsrc = ((size_t)bh * 64 + rowg + srow) * 512 + kt * 64 + schunk;
            gload16(qh + ksrc, &Kh[rowg * 64]);
            gload16(qm + ksrc, &Km[rowg * 64]);
            gload16(vth + vsrc, &Vh[rowg * 64]);
            gload16(vtm + vsrc, &Vm[rowg * 64]);
        }
        __syncthreads();

        #pragma unroll
        for (int i = 0; i < 4; ++i) {
            f32x4 s[4] = {};
            #pragma unroll
            for (int kk = 0; kk < 2; ++kk) {
                #pragma unroll
                for (int j = 0; j < 4; ++j) {
                    int krow = j * 16 + lr;
                    int uk = krow * 64 + (((kk * 4 + g) ^ (krow & 7)) * 8);
                    v8bf bkh = *reinterpret_cast<const v8bf*>(&Kh[uk]);
                    v8bf bkm = *reinterpret_cast<const v8bf*>(&Km[uk]);
                    s[j] = __builtin_amdgcn_mfma_f32_16x16x32_bf16(aqh[i][kk], bkh, s[j], 0, 0, 0);
                    s[j] = __builtin_amdgcn_mfma_f32_16x16x32_bf16(aqh[i][kk], bkm, s[j], 0, 0, 0);
                    s[j] = __builtin_amdgcn_mfma_f32_16x16x32_bf16(aqm[i][kk], bkh, s[j], 0, 0, 0);
                }
            }
            float mnew[4], alpha[4], rsum[4];
            #pragma unroll
            for (int rr = 0; rr < 4; ++rr) {
                float t = fmaxf(fmaxf(s[0][rr], s[1][rr]), fmaxf(s[2][rr], s[3][rr])) * 0.125f;
                #pragma unroll
                for (int off = 1; off < 16; off <<= 1) t = fmaxf(t, __shfl_xor(t, off));
                mnew[rr] = fmaxf(m_run[i][rr], t);
                alpha[rr] = __expf(m_run[i][rr] - mnew[rr]);
                m_run[i][rr] = mnew[rr];
                rsum[rr] = 0.0f;
            }
            #pragma unroll
            for (int j = 0; j < 4; ++j) {
                #pragma unroll
                for (int rr = 0; rr < 4; ++rr) {
                    float p = __expf(s[j][rr] * 0.125f - mnew[rr]);
                    rsum[rr] += p;
                    int prow = 4 * g + rr;
                    int ub = prow * 64 + ((((j * 2 + (lr >> 3)) ^ (prow & 7)) << 3) | (lr & 7));
                    unsigned int pk = split_pack(p);
                    Ph[wave][ub] = (unsigned short)pk; Pm[wave][ub] = (unsigned short)(pk >> 16);
                }
            }
            #pragma unroll
            for (int rr = 0; rr < 4; ++rr) {
                float t = rsum[rr];
                #pragma unroll
                for (int off = 1; off < 16; off <<= 1) t += __shfl_xor(t, off);
                l_run[i][rr] = l_run[i][rr] * alpha[rr] + t;
                O[i][0][rr] *= alpha[rr]; O[i][1][rr] *= alpha[rr];
                O[i][2][rr] *= alpha[rr]; O[i][3][rr] *= alpha[rr];
            }
            #pragma unroll
            for (int kk = 0; kk < 2; ++kk) {
                int up = lr * 64 + (((kk * 4 + g) ^ (lr & 7)) * 8);
                v8bf aph = *reinterpret_cast<const v8bf*>(&Ph[wave][up]);
                v8bf apm = *reinterpret_cast<const v8bf*>(&Pm[wave][up]);
                #pragma unroll
                for (int j = 0; j < 4; ++j) {
                    int vrow = j * 16 + lr;
                    int uv = vrow * 64 + (((kk * 4 + g) ^ (vrow & 7)) * 8);
                    v8bf bvh = *reinterpret_cast<const v8bf*>(&Vh[uv]);
                    v8bf bvm = *reinterpret_cast<const v8bf*>(&Vm[uv]);
                    O[i][j] = __builtin_amdgcn_mfma_f32_16x16x32_bf16(aph, bvh, O[i][j], 0, 0, 0);
                    O[i][j] = __builtin_amdgcn_mfma_f32_16x16x32_bf16(aph, bvm, O[i][j], 0, 0, 0);
                    O[i][j] = __builtin_amdgcn_mfma_f32_16x16x32_bf16(apm, bvh, O[i][j], 0, 0, 0);
                }
            }
        }
    }
    #pragma unroll
    for (int i = 0; i < 4; ++i)
        #pragma unroll
        for (int j = 0; j < 4; ++j) {
            int d = j * 16 + lr;
            #pragma unroll
            for (int rr = 0; rr < 4; ++rr) {
                size_t tok = rowbase + qbase + i * 16 + 4 * g + rr;
                unsigned int pk = split_pack(O[i][j][rr] / l_run[i][rr]);
                ohp[tok * HD + h * 64 + d] = (unsigned short)pk;
                omp[tok * HD + h * 64 + d] = (unsigned short)(pk >> 16);
            }
        }
}

// ---------------------------------------------------------------------------
// x = LayerNorm((xh+xm) + t) * g + b -> (xh, xm). One wave per token.
// ---------------------------------------------------------------------------
__global__ __launch_bounds__(256)
void ln_residual_kernel(unsigned short* __restrict__ xh, unsigned short* __restrict__ xm,
                        const float* __restrict__ t,
                        const float* __restrict__ gamma, const float* __restrict__ beta)
{
    int tok = blockIdx.x * 4 + (threadIdx.x >> 6);
    int lane = threadIdx.x & 63;
    size_t base = (size_t)tok * HD + lane * 12;
    int cb = lane * 12;
    us4 h4[3], m4[3]; f32x4 t4[3];
    #pragma unroll
    for (int q = 0; q < 3; ++q) {
        h4[q] = *reinterpret_cast<const us4*>(&xh[base + q * 4]);
        m4[q] = *reinterpret_cast<const us4*>(&xm[base + q * 4]);
        t4[q] = *reinterpret_cast<const f32x4*>(&t[base + q * 4]);
    }
    float v[12];
    float s = 0.0f;
    #pragma unroll
    for (int k = 0; k < 12; ++k) {
        v[k] = bf2f(h4[k >> 2][k & 3]) + bf2f(m4[k >> 2][k & 3]) + t4[k >> 2][k & 3];
        s += v[k];
    }
    #pragma unroll
    for (int off = 32; off; off >>= 1) s += __shfl_xor(s, off);
    float mean = s * (1.0f / 768.0f);
    float vs = 0.0f;
    #pragma unroll
    for (int k = 0; k < 12; ++k) { float d = v[k] - mean; vs += d * d; }
    #pragma unroll
    for (int off = 32; off; off >>= 1) vs += __shfl_xor(vs, off);
    float rstd = rsqrtf(vs * (1.0f / 768.0f) + 1e-5f);
    f32x4 ga[3], be[3];
    #pragma unroll
    for (int q = 0; q < 3; ++q) {
        ga[q] = *reinterpret_cast<const f32x4*>(&gamma[cb + q * 4]);
        be[q] = *reinterpret_cast<const f32x4*>(&beta[cb + q * 4]);
    }
    us4 oh[3], om[3];
    #pragma unroll
    for (int k = 0; k < 12; ++k) {
        float y = (v[k] - mean) * rstd * ga[k >> 2][k & 3] + be[k >> 2][k & 3];
        unsigned int pk = split_pack(y);
        oh[k >> 2][k & 3] = (unsigned short)pk;
        om[k >> 2][k & 3] = (unsigned short)(pk >> 16);
    }
    #pragma unroll
    for (int q = 0; q < 3; ++q) {
        *reinterpret_cast<us4*>(&xh[base + q * 4]) = oh[q];
        *reinterpret_cast<us4*>(&xm[base + q * 4]) = om[q];
    }
}

__global__ __launch_bounds__(256)
void embed_kernel(const int* __restrict__ ids, const float* __restrict__ emb,
                  unsigned short* __restrict__ xh, unsigned short* __restrict__ xm)
{
    int f4 = blockIdx.x * 256 + threadIdx.x;     // 8192*192 float4
    int tok = f4 / 192, c = f4 % 192;
    float4 v = *reinterpret_cast<const float4*>(emb + (size_t)ids[tok] * HD + c * 4);
    us4 hv, mv; unsigned int p;
    p = split_pack(v.x); hv[0] = (unsigned short)p; mv[0] = (unsigned short)(p >> 16);
    p = split_pack(v.y); hv[1] = (unsigned short)p; mv[1] = (unsigned short)(p >> 16);
    p = split_pack(v.z); hv[2] = (unsigned short)p; mv[2] = (unsigned short)(p >> 16);
    p = split_pack(v.w); hv[3] = (unsigned short)p; mv[3] = (unsigned short)(p >> 16);
    *reinterpret_cast<us4*>(&xh[(size_t)tok * HD + c * 4]) = hv;
    *reinterpret_cast<us4*>(&xm[(size_t)tok * HD + c * 4]) = mv;
}

// ---------------------------------------------------------------------------
// Fused: logits f32 = xh+xm (write to out) AND emis = x @ hw^T + hb.
// One wave per token; x read once.
// ---------------------------------------------------------------------------
__global__ __launch_bounds__(256)
void emis_logits_kernel(const unsigned short* __restrict__ xh, const unsigned short* __restrict__ xm,
                        const float* __restrict__ hw, const float* __restrict__ hb,
                        float* __restrict__ emis, float* __restrict__ out)
{
    int tok = blockIdx.x * 4 + (threadIdx.x >> 6);
    int lane = threadIdx.x & 63;
    size_t base = (size_t)tok * HD + lane * 12;
    int cb = lane * 12;
    us4 h4[3], m4[3];
    #pragma unroll
    for (int q = 0; q < 3; ++q) {
        h4[q] = *reinterpret_cast<const us4*>(&xh[base + q * 4]);
        m4[q] = *reinterpret_cast<const us4*>(&xm[base + q * 4]);
    }
    float xv[12];
    #pragma unroll
    for (int k = 0; k < 12; ++k)
        xv[k] = bf2f(h4[k >> 2][k & 3]) + bf2f(m4[k >> 2][k & 3]);
    // logits write (f32)
    #pragma unroll
    for (int q = 0; q < 3; ++q) {
        f32x4 o;
        o[0] = xv[q * 4 + 0]; o[1] = xv[q * 4 + 1];
        o[2] = xv[q * 4 + 2]; o[3] = xv[q * 4 + 3];
        *reinterpret_cast<f32x4*>(&out[base + q * 4]) = o;
    }
    // emissions
    for (int t = 0; t < TT; ++t) {
        f32x4 w4[3];
        #pragma unroll
        for (int q = 0; q < 3; ++q)
            w4[q] = *reinterpret_cast<const f32x4*>(&hw[t * HD + cb + q * 4]);
        float a = 0.0f;
        #pragma unroll
        for (int k = 0; k < 12; ++k) a += xv[k] * w4[k >> 2][k & 3];
        #pragma unroll
        for (int off = 32; off; off >>= 1) a += __shfl_xor(a, off);
        if (lane == 0) emis[(size_t)tok * TT + t] = a + hb[t];
    }
}

__global__ void crf_num_kernel(const float* __restrict__ emis, const int* __restrict__ labels,
                               const float* __restrict__ start, const float* __restrict__ end,
                               const float* __restrict__ trans, float* __restrict__ num)
{
    int b = blockIdx.x, lane = threadIdx.x;   // blockDim 64
    float a = 0.0f;
    for (int s = lane; s < 512; s += 64) {
        int lab = labels[b * 512 + s];
        a += emis[(size_t)(b * 512 + s) * TT + lab];
        if (s > 0) a += trans[labels[b * 512 + s - 1] * TT + lab];
        else a += start[lab];
        if (s == 511) a += end[lab];
    }
    #pragma unroll
    for (int off = 32; off; off >>= 1) a += __shfl_xor(a, off);
    if (lane == 0) num[b] = a;
}

// ---------------------------------------------------------------------------
// Fused CRF forward + viterbi (v4 — best measured: 214 us).
// Forward: r via readfirstlane, 1 exp/lane, 1 LDS trip, tree dot.
// Viterbi: hot loop = value-max only (exact) + score history in LDS;
//          phase 2 computes the argmax table fully parallel (64 lanes);
//          lane-0 backtrack. Same first-max semantics as the serial reference.
// ---------------------------------------------------------------------------
__global__ __launch_bounds__(64)
void crf_path_kernel(const float* __restrict__ emis, const float* __restrict__ start,
                     const float* __restrict__ end, const float* __restrict__ trans,
                     float* __restrict__ logZ, float* __restrict__ out_tags)
{
    const int mode = blockIdx.x >> 4;
    const int b = blockIdx.x & 15;
    const int lane = threadIdx.x;
    const int j = lane & 31;
    __shared__ float xch[32];
    __shared__ float shist[512 * 32];            // viterbi score history (64 KB)
    __shared__ unsigned char hist[511][32];
    __shared__ float sval[32];
    __shared__ int path[512];

    const float* eb = emis + (size_t)b * 512 * TT;

    if (mode == 0) {
        if (lane < 32) {
            float Ecol[32];
            #pragma unroll
            for (int ii = 0; ii < 32; ++ii) Ecol[ii] = __expf(trans[ii * TT + j]);
            float cur[8], nxt[8];
            #pragma unroll
            for (int i = 0; i < 8; ++i) cur[i] = eb[(1 + i) * TT + j];
            float sc = start[j] + eb[j];
            for (int base = 1; base < 512; base += 8) {
                #pragma unroll
                for (int i = 0; i < 8; ++i) {
                    int s = base + 8 + i;
                    nxt[i] = eb[(s < 512 ? s : 511) * TT + j];
                }
                #pragma unroll
                for (int i = 0; i < 8; ++i) {
                    if (base + i < 512) {
                        float r = __uint_as_float(
                            __builtin_amdgcn_readfirstlane(__float_as_uint(sc)));
                        float p = __expf(sc - r);
                        xch[j] = p;
                        asm volatile("s_waitcnt lgkmcnt(0)" ::: "memory");
                        f32x4 tt[8];
                        #pragma unroll
                        for (int q = 0; q < 8; ++q)
                            tt[q] = *reinterpret_cast<const f32x4*>(&xch[q * 4]);
                        asm volatile("" ::: "memory");
                        float mm[16];
                        #pragma unroll
                        for (int q = 0; q < 16; ++q)
                            mm[q] = fmaf(tt[(2 * q + 1) >> 2][(2 * q + 1) & 3], Ecol[2 * q + 1],
                                         tt[(2 * q) >> 2][(2 * q) & 3] * Ecol[2 * q]);
                        float s8[8];
                        #pragma unroll
                        for (int q = 0; q < 8; ++q) s8[q] = mm[2 * q] + mm[2 * q + 1];
                        float s4[4];
                        #pragma unroll
                        for (int q = 0; q < 4; ++q) s4[q] = s8[2 * q] + s8[2 * q + 1];
                        float dot = (s4[0] + s4[1]) + (s4[2] + s4[3]);
                        sc = r + __logf(dot) + cur[i];
                    }
                }
                #pragma unroll
                for (int i = 0; i < 8; ++i) cur[i] = nxt[i];
            }
            float v = sc + end[j];
            float mx = v;
            #pragma unroll
            for (int off = 1; off < 32; off <<= 1) mx = fmaxf(mx, __shfl_xor(mx, off));
            float p = __expf(v - mx);
            float sm = p;
            #pragma unroll
            for (int off = 1; off < 32; off <<= 1) sm += __shfl_xor(sm, off);
            if (lane == 0) logZ[b] = mx + __logf(sm);
        }
    } else {
        // all 64 lanes preload trans column j (lanes j and j+32 share j)
        float tcol[32];
        #pragma unroll
        for (int ii = 0; ii < 32; ++ii) tcol[ii] = trans[ii * TT + j];

        // phase 1 (lanes 0..31): value-max recursion, store score history
        if (lane < 32) {
            float cur[8], nxt[8];
            #pragma unroll
            for (int i = 0; i < 8; ++i) cur[i] = eb[(1 + i) * TT + j];
            float sc = start[j] + eb[j];
            shist[0 * 32 + j] = sc;
            for (int base = 1; base < 512; base += 8) {
                #pragma unroll
                for (int i = 0; i < 8; ++i) {
                    int s = base + 8 + i;
                    nxt[i] = eb[(s < 512 ? s : 511) * TT + j];
                }
                #pragma unroll
                for (int i = 0; i < 8; ++i) {
                    if (base + i < 512) {
                        xch[j] = sc;
                        asm volatile("s_waitcnt lgkmcnt(0)" ::: "memory");
                        f32x4 tt[8];
                        #pragma unroll
                        for (int q = 0; q < 8; ++q)
                            tt[q] = *reinterpret_cast<const f32x4*>(&xch[q * 4]);
                        asm volatile("" ::: "memory");
                        float c[32];
                        #pragma unroll
                        for (int ii = 0; ii < 32; ++ii)
                            c[ii] = tt[ii >> 2][ii & 3] + tcol[ii];
                        float v1[16];
                        #pragma unroll
                        for (int q = 0; q < 16; ++q) v1[q] = fmaxf(c[2 * q], c[2 * q + 1]);
                        float v2[8];
                        #pragma unroll
                        for (int q = 0; q < 8; ++q) v2[q] = fmaxf(v1[2 * q], v1[2 * q + 1]);
                        float v3[4];
                        #pragma unroll
                        for (int q = 0; q < 4; ++q) v3[q] = fmaxf(v2[2 * q], v2[2 * q + 1]);
                        float best = fmaxf(fmaxf(v3[0], v3[1]), fmaxf(v3[2], v3[3]));
                        sc = best + cur[i];
                        shist[(base + i) * 32 + j] = sc;
                    }
                }
                #pragma unroll
                for (int i = 0; i < 8; ++i) cur[i] = nxt[i];
            }
            sval[j] = sc + end[j];
        }
        __syncthreads();

        // phase 2 (all 64 lanes): argmax table, first-max semantics
        const int h = lane >> 5;
        for (int it = 0; it < 256; ++it) {
            int s = 1 + 2 * it + h;
            if (s < 512) {
                const float* pr = &shist[(s - 1) * 32];
                float c[32];
                #pragma unroll
                for (int q = 0; q < 8; ++q) {
                    f32x4 t4 = *reinterpret_cast<const f32x4*>(&pr[q * 4]);
                    c[q * 4 + 0] = t4[0] + tcol[q * 4 + 0];
                    c[q * 4 + 1] = t4[1] + tcol[q * 4 + 1];
                    c[q * 4 + 2] = t4[2] + tcol[q * 4 + 2];
                    c[q * 4 + 3] = t4[3] + tcol[q * 4 + 3];
                }
                float v1[16]; int a1[16];
                #pragma unroll
                for (int q = 0; q < 16; ++q) {
                    bool ge = c[2 * q] >= c[2 * q + 1];
                    v1[q] = ge ? c[2 * q] : c[2 * q + 1];
                    a1[q] = ge ? 2 * q : 2 * q + 1;
                }
                float v2[8]; int a2[8];
                #pragma unroll
                for (int q = 0; q < 8; ++q) {
                    bool ge = v1[2 * q] >= v1[2 * q + 1];
                    v2[q] = ge ? v1[2 * q] : v1[2 * q + 1];
                    a2[q] = ge ? a1[2 * q] : a1[2 * q + 1];
                }
                float v3[4]; int a3[4];
                #pragma unroll
                for (int q = 0; q < 4; ++q) {
                    bool ge = v2[2 * q] >= v2[2 * q + 1];
                    v3[q] = ge ? v2[2 * q] : v2[2 * q + 1];
                    a3[q] = ge ? a2[2 * q] : a2[2 * q + 1];
                }
                float v4[2]; int a4[2];
                #pragma unroll
                for (int q = 0; q < 2; ++q) {
                    bool ge = v3[2 * q] >= v3[2 * q + 1];
                    v4[q] = ge ? v3[2 * q] : v3[2 * q + 1];
                    a4[q] = ge ? a3[2 * q] : a3[2 * q + 1];
                }
                bool ge = v4[0] >= v4[1];
                int arg = ge ? a4[0] : a4[1];
                hist[s - 1][j] = (unsigned char)arg;
            }
        }
        __syncthreads();

        if (lane == 0) {
            float best = sval[0]; int arg = 0;
            for (int i = 1; i < TT; ++i)
                if (sval[i] > best) { best = sval[i]; arg = i; }
            int t = arg; path[511] = t;
            for (int s = 510; s >= 0; --s) { t = hist[s][t]; path[s] = t; }
        }
        __syncthreads();
        for (int s = lane; s < 512; s += 64)
            out_tags[(size_t)b * 512 + s] = (float)path[s];
    }
}

__global__ void crf_loss_kernel(const float* __restrict__ num, const float* __restrict__ logZ,
                                float* __restrict__ out)
{
    if (threadIdx.x == 0) {
        float s = 0.0f;
        for (int b = 0; b < 16; ++b) s += num[b] - logZ[b];
        out[0] = -s / 10000.0f;
    }
}

extern "C" void kernel_launch(void* const* d_in, const int* in_sizes, int n_in,
                              void* d_out, int out_size, void* d_ws, size_t ws_size,
                              hipStream_t stream)
{
    (void)in_sizes; (void)n_in; (void)out_size; (void)ws_size;
    const int*   input_ids = (const int*)d_in[0];
    const int*   labels    = (const int*)d_in[1];
    const float* emb   = (const float*)d_in[3];
    const float* in_w  = (const float*)d_in[4];
    const float* in_b  = (const float*)d_in[5];
    const float* out_w = (const float*)d_in[6];
    const float* out_b = (const float*)d_in[7];
    const float* ln1g  = (const float*)d_in[8];
    const float* ln1b  = (const float*)d_in[9];
    const float* ln2g  = (const float*)d_in[10];
    const float* ln2b  = (const float*)d_in[11];
    const float* w1    = (const float*)d_in[12];
    const float* b1    = (const float*)d_in[13];
    const float* w2    = (const float*)d_in[14];
    const float* b2    = (const float*)d_in[15];
    const float* hw    = (const float*)d_in[16];
    const float* hb    = (const float*)d_in[17];
    const float* cs    = (const float*)d_in[18];
    const float* ce    = (const float*)d_in[19];
    const float* ct    = (const float*)d_in[20];
    float* out = (float*)d_out;

    char* ws = (char*)d_ws;
    unsigned short* xh   = (unsigned short*)(ws);
    unsigned short* xm   = (unsigned short*)(ws + 12582912);
    unsigned short* qkvh = (unsigned short*)(ws + 25165824);
    unsigned short* qkvm = (unsigned short*)(ws + 62914560);
    unsigned short* ohb  = (unsigned short*)(ws + 100663296);
    unsigned short* omb  = (unsigned short*)(ws + 113246208);
    float*          tmp  = (float*)(ws + 125829120);
    unsigned short* vth  = (unsigned short*)(ws + 125829120);  // alias tmp (disjoint lifetime)
    unsigned short* vtm  = (unsigned short*)(ws + 138412032);
    unsigned short* wih  = (unsigned short*)(ws + 150994944);
    unsigned short* wim  = (unsigned short*)(ws + 154533888);
    unsigned short* woh  = (unsigned short*)(ws + 158072832);
    unsigned short* wom  = (unsigned short*)(ws + 159252480);
    unsigned short* w1h  = (unsigned short*)(ws + 160432128);
    unsigned short* w1m  = (unsigned short*)(ws + 161611776);
    unsigned short* w2h  = (unsigned short*)(ws + 162791424);
    unsigned short* w2m  = (unsigned short*)(ws + 163971072);
    unsigned short* f1h  = qkvh;   // qkv dead after attn
    unsigned short* f1m  = qkvm;
    float* emis = (float*)(ws + 100663296);                // alias ohb (dead post-encoder)
    float* numb = (float*)(ws + 100663296 + 1048576);
    float* logZ = numb + 16;

    embed_kernel<<<MTOK * 192 / 256, 256, 0, stream>>>(input_ids, emb, xh, xm);

    for (int l = 0; l < NL; ++l) {
        wsplit4_kernel<<<3456, 256, 0, stream>>>(
            in_w + (size_t)l * H3 * HD, out_w + (size_t)l * HD * HD,
            w1 + (size_t)l * HD * HD, w2 + (size_t)l * HD * HD,
            wih, wim, woh, wom, w1h, w1m, w2h, w2m);

        gemm_pair_kernel<false, true><<<dim3(18, 64), 256, 0, stream>>>(
            xh, xm, wih, wim, in_b + (size_t)l * H3, nullptr, qkvh, qkvm, H3);
        vtrans_kernel<<<dim3(8, 192), 256, 0, stream>>>(qkvh, qkvm, vth, vtm);
        attn_kernel<<<dim3(2, 192), 256, 0, stream>>>(qkvh, qkvm, vth, vtm, ohb, omb);
        gemm_pair_kernel<false, false><<<dim3(6, 64), 256, 0, stream>>>(
            ohb, omb, woh, wom, out_b + (size_t)l * HD, tmp, nullptr, nullptr, HD);
        ln_residual_kernel<<<2048, 256, 0, stream>>>(xh, xm, tmp, ln1g + l * HD, ln1b + l * HD);
        gemm_pair_kernel<true, true><<<dim3(6, 64), 256, 0, stream>>>(
            xh, xm, w1h, w1m, b1 + (size_t)l * HD, nullptr, f1h, f1m, HD);
        gemm_pair_kernel<false, false><<<dim3(6, 64), 256, 0, stream>>>(
            f1h, f1m, w2h, w2m, b2 + (size_t)l * HD, tmp, nullptr, nullptr, HD);
        ln_residual_kernel<<<2048, 256, 0, stream>>>(xh, xm, tmp, ln2g + l * HD, ln2b + l * HD);
    }

    emis_logits_kernel<<<2048, 256, 0, stream>>>(xh, xm, hw, hb, emis, out);
    crf_num_kernel<<<16, 64, 0, stream>>>(emis, labels, cs, ce, ct, numb);
    crf_path_kernel<<<32, 64, 0, stream>>>(emis, cs, ce, ct, logZ, out + 6291457);
    crf_loss_kernel<<<1, 64, 0, stream>>>(numb, logZ, out + 6291456);
}